// Round 6
// baseline (403.559 us; speedup 1.0000x reference)
//
#include <hip/hip_runtime.h>
#include <cstdint>
#include <math.h>
#include <string.h>

typedef unsigned short us;
typedef __attribute__((ext_vector_type(8))) __bf16 bf16x8;
typedef __attribute__((ext_vector_type(8))) unsigned short ushort8;
typedef __attribute__((ext_vector_type(4))) float f32x4;

__device__ __forceinline__ us f2bf(float x){
  union { float f; unsigned int u; } v; v.f = x;
  unsigned int r = v.u + 0x7FFFu + ((v.u >> 16) & 1u);   // RNE
  return (us)(r >> 16);
}
__device__ __forceinline__ float b2f(us u){
  union { unsigned int u; float f; } v; v.u = ((unsigned int)u) << 16; return v.f;
}
__device__ __forceinline__ void split2(float x, us& hi, us& lo){
  hi = f2bf(x); lo = f2bf(x - b2f(hi));
}
__device__ __forceinline__ f32x4 fzero(){ f32x4 v; v.x=0.f; v.y=0.f; v.z=0.f; v.w=0.f; return v; }
__device__ __forceinline__ f32x4 mfma16(bf16x8 a, bf16x8 b, f32x4 c){
  return __builtin_amdgcn_mfma_f32_16x16x32_bf16(a, b, c, 0, 0, 0);
}
__device__ __forceinline__ void gload_lds16(const void* g, void* l){
  __builtin_amdgcn_global_load_lds(
      (const __attribute__((address_space(1))) unsigned int*)(uintptr_t)g,
      (__attribute__((address_space(3))) unsigned int*)(uintptr_t)l,
      16, 0, 0);
}

// exp2-folded scales
#define QS2 (0.07216878364870322f * 1.4426950408889634f)   // 1/sqrt(192) * log2(e)
#define BS  (0.08838834764831845f * 1.4426950408889634f)   // 1/sqrt(128) * log2(e)

// ---------------- 1: fp32 -> bf16 (hi only) ----------------
__global__ __launch_bounds__(256) void k_convx(const float* __restrict__ xq,
                                               const float* __restrict__ xkv,
                                               us* __restrict__ qhi,
                                               us* __restrict__ kvhi)
{
  int i = blockIdx.x * 256 + threadIdx.x;   // float4 units, 2M total
  const float* src; us* dh;
  if (i < 1048576){ src = xq  + (size_t)i*4;           dh = qhi  + (size_t)i*4; }
  else            { src = xkv + (size_t)(i-1048576)*4; dh = kvhi + (size_t)(i-1048576)*4; }
  f32x4 v = *(const f32x4*)src;
  dh[0]=f2bf(v.x); dh[1]=f2bf(v.y); dh[2]=f2bf(v.z); dh[3]=f2bf(v.w);
}

// ---------------- 2: weight transpose + split: Wt[n][k] (lo only for Wv,Wo) ----------------
__global__ __launch_bounds__(256) void k_convw(const float* w0, const float* w1, const float* w2,
                                               const float* w3, const float* w4, const float* w5,
                                               us* __restrict__ wt)
{
  __shared__ float tile[32][33];
  int z = blockIdx.z;
  const float* W = (z==0)?w0:(z==1)?w1:(z==2)?w2:(z==3)?w3:(z==4)?w4:w5;
  us* dst_hi = wt + (size_t)z * 2097152;
  us* dst_lo = dst_hi + 1048576;
  bool wlo = (z == 2) || (z == 5);
  int n0 = blockIdx.x * 32, k0 = blockIdx.y * 32;
  int c = threadIdx.x & 31, r = threadIdx.x >> 5;
#pragma unroll
  for (int i = 0; i < 4; i++)
    tile[r + i*8][c] = W[(size_t)(k0 + r + i*8)*1024 + n0 + c];
  __syncthreads();
#pragma unroll
  for (int i = 0; i < 4; i++){
    int nn = r + i*8;
    us h,l; split2(tile[c][nn], h, l);
    dst_hi[(size_t)(n0 + nn)*1024 + k0 + c] = h;
    if (wlo) dst_lo[(size_t)(n0 + nn)*1024 + k0 + c] = l;
  }
}

// ---------------- 3: layernorm(rel_emb) -> bf16 hi ----------------
__global__ __launch_bounds__(256) void k_lnrel(const float* __restrict__ rel,
                                               const float* __restrict__ g,
                                               const float* __restrict__ b,
                                               us* __restrict__ out_hi)
{
  __shared__ float sm[8];
  int row = blockIdx.x, t = threadIdx.x;
  const float* x = rel + (size_t)row * 1024;
  float v[4]; float s = 0.f, ss = 0.f;
#pragma unroll
  for (int i=0;i<4;i++){ v[i] = x[t + 256*i]; s += v[i]; ss += v[i]*v[i]; }
  for (int o=32;o;o>>=1){ s += __shfl_xor(s,o); ss += __shfl_xor(ss,o); }
  int w = t >> 6;
  if ((t & 63) == 0){ sm[w] = s; sm[4+w] = ss; }
  __syncthreads();
  s  = sm[0]+sm[1]+sm[2]+sm[3];
  ss = sm[4]+sm[5]+sm[6]+sm[7];
  float mu  = s  * (1.0f/1024.0f);
  float var = ss * (1.0f/1024.0f) - mu*mu;
  float rs  = rsqrtf(var + 1e-5f);
#pragma unroll
  for (int i=0;i<4;i++){
    int cc = t + 256*i;
    out_hi[(size_t)row*1024 + cc] = f2bf((v[i]-mu)*rs*g[cc] + b[cc]);
  }
}

// ---------------- 4: log-bucket idx table, padded to 2052 for dword reads ----------------
__global__ void k_bucket(signed char* __restrict__ idxt)
{
  int i = blockIdx.x * 256 + threadIdx.x;
  if (i >= 2052) return;
  int d = i - 1023;
  int ad = d < 0 ? -d : d;
  int abspos = (d < 16 && d > -16) ? 15 : ad;
  int bucket;
  if (abspos <= 16) bucket = d;
  else {
    float num = (float)log((double)abspos * 0.0625);
    float den = (float)log(7.9375);
    float lp = ceilf(num / den * 15.0f) + 16.0f;
    bucket = (int)lp * (d > 0 ? 1 : -1);
  }
  int s = bucket + 32;
  s = s < 0 ? 0 : (s > 63 ? 63 : s);
  idxt[i] = (signed char)s;
}

// ---------------- 5a: merged QKV GEMM: BM=128, BN=64, 4 waves ----------------
// cls 0: Q = Xq@Wq (NKT 32, out [B,H,T,HD]); cls 1: K (NKT 32, same layout);
// cls 2: V = Xkv@(Wv_hi+Wv_lo) (NKT 64, out [B,H,HD,T])
__global__ __launch_bounds__(256, 4) void k_qkv(const us* __restrict__ Xq, const us* __restrict__ Xkv,
                                                const us* __restrict__ wt,
                                                const float* __restrict__ bq, const float* __restrict__ bk,
                                                const float* __restrict__ bv,
                                                us* __restrict__ qbuf, us* __restrict__ kbuf,
                                                us* __restrict__ vtb)
{
  __shared__ __align__(16) us a_lds[2][4096];   // 128 x 32
  __shared__ __align__(16) us b_lds[2][2048];   // 64 x 32
  int bid = blockIdx.x;
  int wg = (bid & 7) * 192 + (bid >> 3);        // XCD swizzle, 1536 % 8 == 0
  int cls = wg >> 9, tix = wg & 511;
  int mt = tix >> 4, nt = tix & 15;
  int m0 = mt * 128, n0 = nt * 64;
  const us* A  = (cls == 0) ? Xq : Xkv;
  const us* Bh = wt + (size_t)cls * 2097152;
  const us* Bl = Bh + 1048576;
  const float* bias = (cls==0) ? bq : (cls==1) ? bk : bv;
  const int NKT = (cls == 2) ? 64 : 32;
  int t = threadIdx.x, w = t >> 6, lane = t & 63, lg = lane >> 4, li = lane & 15;
  int wm = w >> 1, wn = w & 1;
  f32x4 acc[4][2];
#pragma unroll
  for (int i=0;i<4;i++){ acc[i][0]=fzero(); acc[i][1]=fzero(); }

  auto stage = [&](int buf, int kt){
    int seg = kt >> 5, k0 = (kt & 31) * 32;
    const us* Bp = seg ? Bl : Bh;
#pragma unroll
    for (int c = 0; c < 2; c++){
      int slot = c*256 + t;
      int g = slot ^ ((slot >> 3) & 7);
      int r = g >> 2, kc = g & 3;
      gload_lds16(A + (size_t)(m0 + r)*1024 + k0 + kc*8, (char*)&a_lds[buf][0] + slot*16);
    }
    {
      int slot = t;
      int g = slot ^ ((slot >> 3) & 7);
      int r = g >> 2, kc = g & 3;
      gload_lds16(Bp + (size_t)(n0 + r)*1024 + k0 + kc*8, (char*)&b_lds[buf][0] + slot*16);
    }
  };

  stage(0, 0);
  __syncthreads();
  int buf = 0;
  for (int kt = 0; kt < NKT; kt++){
    if (kt + 1 < NKT) stage(buf ^ 1, kt + 1);
    bf16x8 af[4], bfv[2];
#pragma unroll
    for (int mi=0;mi<4;mi++){
      int r = wm*64 + mi*16 + li;
      int s = (r*4 + lg); s ^= ((s >> 3) & 7);
      af[mi] = *(const bf16x8*)((char*)&a_lds[buf][0] + s*16);
    }
#pragma unroll
    for (int ni=0;ni<2;ni++){
      int r = wn*32 + ni*16 + li;
      int s = (r*4 + lg); s ^= ((s >> 3) & 7);
      bfv[ni] = *(const bf16x8*)((char*)&b_lds[buf][0] + s*16);
    }
#pragma unroll
    for (int mi=0;mi<4;mi++)
#pragma unroll
      for (int ni=0;ni<2;ni++)
        acc[mi][ni] = mfma16(af[mi], bfv[ni], acc[mi][ni]);
    __syncthreads();
    buf ^= 1;
  }

#pragma unroll
  for (int ni=0;ni<2;ni++){
    int n = n0 + wn*32 + ni*16 + li;
    float bn = bias[n];
    int hh = n >> 6, hd = n & 63;
#pragma unroll
    for (int mi=0;mi<4;mi++){
      int mb = m0 + wm*64 + mi*16 + lg*4;
#pragma unroll
      for (int j=0;j<4;j++){
        int m = mb + j;
        float val = acc[mi][ni][j] + bn;
        int bb = m >> 10, tp = m & 1023;
        if (cls == 2)
          vtb[(((size_t)(bb*16 + hh))*64 + hd)*1024 + tp] = f2bf(val);
        else {
          us* out = cls ? kbuf : qbuf;
          out[(((size_t)(bb*16 + hh))*1024 + tp)*64 + hd] = f2bf(val);
        }
      }
    }
  }
}

// ---------------- 5b: O GEMM: 3 products, BM=128, BN=64, fp32 out ----------------
__global__ __launch_bounds__(256, 2) void k_gemmo(const us* __restrict__ A_hi, const us* __restrict__ A_lo,
                                                  const us* __restrict__ B_hi, const us* __restrict__ B_lo,
                                                  const float* __restrict__ bias,
                                                  float* __restrict__ out_f)
{
  __shared__ __align__(16) us a_lds[2][4096];
  __shared__ __align__(16) us b_lds[2][2048];
  int bid = blockIdx.x;
  int wg = (bid & 7) * 64 + (bid >> 3);        // 512 % 8 == 0
  int mt = wg >> 4, nt = wg & 15;
  int m0 = mt * 128, n0 = nt * 64;
  int t = threadIdx.x, w = t >> 6, lane = t & 63, lg = lane >> 4, li = lane & 15;
  int wm = w >> 1, wn = w & 1;
  f32x4 acc[4][2];
#pragma unroll
  for (int i=0;i<4;i++){ acc[i][0]=fzero(); acc[i][1]=fzero(); }

  auto stage = [&](int buf, int kt){
    int seg = kt >> 5, k0 = (kt & 31) * 32;
    const us* Ap = (seg == 2) ? A_lo : A_hi;
    const us* Bp = (seg == 1) ? B_lo : B_hi;
#pragma unroll
    for (int c = 0; c < 2; c++){
      int slot = c*256 + t;
      int g = slot ^ ((slot >> 3) & 7);
      int r = g >> 2, kc = g & 3;
      gload_lds16(Ap + (size_t)(m0 + r)*1024 + k0 + kc*8, (char*)&a_lds[buf][0] + slot*16);
    }
    {
      int slot = t;
      int g = slot ^ ((slot >> 3) & 7);
      int r = g >> 2, kc = g & 3;
      gload_lds16(Bp + (size_t)(n0 + r)*1024 + k0 + kc*8, (char*)&b_lds[buf][0] + slot*16);
    }
  };

  stage(0, 0);
  __syncthreads();
  int buf = 0;
  for (int kt = 0; kt < 96; kt++){
    if (kt + 1 < 96) stage(buf ^ 1, kt + 1);
    bf16x8 af[4], bfv[2];
#pragma unroll
    for (int mi=0;mi<4;mi++){
      int r = wm*64 + mi*16 + li;
      int s = (r*4 + lg); s ^= ((s >> 3) & 7);
      af[mi] = *(const bf16x8*)((char*)&a_lds[buf][0] + s*16);
    }
#pragma unroll
    for (int ni=0;ni<2;ni++){
      int r = wn*32 + ni*16 + li;
      int s = (r*4 + lg); s ^= ((s >> 3) & 7);
      bfv[ni] = *(const bf16x8*)((char*)&b_lds[buf][0] + s*16);
    }
#pragma unroll
    for (int mi=0;mi<4;mi++)
#pragma unroll
      for (int ni=0;ni<2;ni++)
        acc[mi][ni] = mfma16(af[mi], bfv[ni], acc[mi][ni]);
    __syncthreads();
    buf ^= 1;
  }

#pragma unroll
  for (int ni=0;ni<2;ni++){
    int n = n0 + wn*32 + ni*16 + li;
    float bn = bias[n];
#pragma unroll
    for (int mi=0;mi<4;mi++){
      int mb = m0 + wm*64 + mi*16 + lg*4;
#pragma unroll
      for (int j=0;j<4;j++)
        out_f[(size_t)(mb + j)*1024 + n] = acc[mi][ni][j] + bn;
    }
  }
}

// ---------------- 6: pos_k/pos_q = LN(rel) @ Wp + bp (single product) ----------------
__global__ __launch_bounds__(256) void k_pos(const us* __restrict__ reln_hi,
                                             const us* __restrict__ wt,
                                             const float* __restrict__ bpk, const float* __restrict__ bpq,
                                             us* __restrict__ posk_hi, us* __restrict__ posq_hi)
{
  int ntile = blockIdx.x;            // 0..15
  int z = blockIdx.y;                // 0: pk (slot 3), 1: pq (slot 4)
  const us* W_hi = wt + (size_t)(3 + z) * 2097152;
  const float* bias = z ? bpq : bpk;
  us* out_hi = z ? posq_hi : posk_hi;
  int t = threadIdx.x, w = t >> 6, lane = t & 63, lg = lane >> 4, li = lane & 15;
  f32x4 acc[4];
#pragma unroll
  for (int i=0;i<4;i++) acc[i] = fzero();
  int srow = w*16 + li;
  for (int kt = 0; kt < 32; kt++){
    int k0 = kt*32 + lg*8;
    bf16x8 a = *(const bf16x8*)(reln_hi + (size_t)srow*1024 + k0);
#pragma unroll
    for (int nf=0; nf<4; nf++){
      int n = ntile*64 + nf*16 + li;
      bf16x8 b = *(const bf16x8*)(W_hi + (size_t)n*1024 + k0);
      acc[nf] = mfma16(a, b, acc[nf]);
    }
  }
#pragma unroll
  for (int nf=0;nf<4;nf++){
    int n = ntile*64 + nf*16 + li;
    float bn = bias[n];
    int h = n >> 6, hd = n & 63;
#pragma unroll
    for (int j=0;j<4;j++){
      int s = w*16 + lg*4 + j;
      out_hi[(size_t)h*4096 + s*64 + hd] = f2bf(acc[nf][j] + bn);
    }
  }
}

// ---------------- 7: c2p/p2c (single product, pre-scaled by BS for exp2) ----------------
__global__ __launch_bounds__(256) void k_cp(const us* __restrict__ q_hi,
                                            const us* __restrict__ k_hi,
                                            const us* __restrict__ pk_hi,
                                            const us* __restrict__ pq_hi,
                                            us* __restrict__ c2p, us* __restrict__ p2c)
{
  int qt = blockIdx.x, bh = blockIdx.y, z = blockIdx.z;
  const us* X_hi = z ? k_hi : q_hi;
  const us* P_hi = z ? pq_hi : pk_hi;
  us* out = z ? p2c : c2p;
  int h = bh & 15;
  int t = threadIdx.x, w = t >> 6, lane = t & 63, lg = lane >> 4, li = lane & 15;
  f32x4 acc[4];
#pragma unroll
  for (int i=0;i<4;i++) acc[i] = fzero();
  size_t row = (size_t)bh*1024 + qt*64 + w*16 + li;
#pragma unroll
  for (int kk=0;kk<2;kk++){
    int k = kk*32 + lg*8;
    bf16x8 ah = *(const bf16x8*)(X_hi + row*64 + k);
#pragma unroll
    for (int nf=0;nf<4;nf++){
      int s = nf*16 + li;
      bf16x8 bh_ = *(const bf16x8*)(P_hi + (size_t)h*4096 + s*64 + k);
      acc[nf] = mfma16(ah, bh_, acc[nf]);
    }
  }
  size_t obase = ((size_t)bh*1024 + qt*64 + w*16 + lg*4) * 64;
#pragma unroll
  for (int nf=0;nf<4;nf++)
#pragma unroll
    for (int j=0;j<4;j++)
      out[obase + (size_t)j*64 + nf*16 + li] = f2bf(acc[nf][j] * BS);
}

// ---------------- 8: fused attention: 4 waves, QBLK=128 (rf=2), far fast path ----------------
__global__ __launch_bounds__(256, 3) void k_attn(const us* __restrict__ qhi,
                                                 const us* __restrict__ khi,
                                                 const us* __restrict__ vhi,
                                                 const us* __restrict__ c2p, const us* __restrict__ p2c,
                                                 const signed char* __restrict__ idxt,
                                                 const unsigned char* __restrict__ mask,
                                                 us* __restrict__ ctx_hi, us* __restrict__ ctx_lo)
{
  __shared__ __align__(16) us khi_lds[4096], vhi_lds[4096];
  __shared__ __align__(16) us c2p_lds[128*72], p2c_lds[64*72];   // 144B row stride
  __shared__ __align__(16) us p_lds[4][1024];

  const int qt = blockIdx.x, bh = blockIdx.y;   // qt: 0..7
  const int b = bh >> 4, h = bh & 15;
  const int t = threadIdx.x, w = t >> 6, lane = t & 63, lg = lane >> 4, li = lane & 15;
  const int q0 = qt * 128;

  {
    const us* src = c2p + ((size_t)bh*1024 + q0) * 64;
#pragma unroll
    for (int c = 0; c < 4; c++){
      int f = c*256 + t, r = f >> 3, kc = f & 7;
      *(ushort8*)&c2p_lds[r*72 + kc*8] = *(const ushort8*)(src + r*64 + kc*8);
    }
  }
  bf16x8 qfh[2][2];
#pragma unroll
  for (int rf=0;rf<2;rf++){
    const us* qph = qhi + ((size_t)bh*1024 + q0 + rf*64 + w*16 + li)*64 + lg*8;
    qfh[rf][0] = *(const bf16x8*)(qph); qfh[rf][1] = *(const bf16x8*)(qph + 32);
  }
  float lrow[2][4];
  f32x4 accO[2][4];
#pragma unroll
  for (int rf=0;rf<2;rf++)
#pragma unroll
    for (int j=0;j<4;j++){ lrow[rf][j] = 0.f; accO[rf][j] = fzero(); }
  const unsigned char* mptr = mask + b*1024;

  for (int kt = 0; kt < 16; kt++){
    const int k0 = kt * 64;
    const bool far = (q0 - k0 >= 192) || (k0 - q0 >= 256);
    __syncthreads();
    {  // stage K,V (512 chunks each, 2 per thread)
#pragma unroll
      for (int c = 0; c < 2; c++){
        int f = c*256 + t, r = f >> 3, kc = f & 7;
        *(ushort8*)&khi_lds[r*64 + ((kc ^ (r & 7))*8)] =
            *(const ushort8*)(khi + ((size_t)bh*1024 + k0 + r)*64 + kc*8);
        *(ushort8*)&vhi_lds[r*64 + ((kc ^ (r & 7))*8)] =
            *(const ushort8*)(vhi + ((size_t)bh*64 + r)*1024 + k0 + kc*8);
        if (!far)
          *(ushort8*)&p2c_lds[r*72 + kc*8] =
              *(const ushort8*)(p2c + ((size_t)bh*1024 + k0 + r)*64 + kc*8);
      }
    }
    __syncthreads();

    // per-kt hoists (independent of rf)
    bool mk[4]; float ckr[4];
    const int cidx = (q0 > k0) ? 63 : 0;
#pragma unroll
    for (int nf=0;nf<4;nf++){
      int kloc = nf*16 + li;
      mk[nf] = mptr[k0 + kloc] != 0;
      if (far) ckr[nf] = b2f(p2c[((size_t)bh*1024 + k0 + kloc)*64 + cidx]);
    }

#pragma unroll
    for (int rf = 0; rf < 2; rf++){
      // QK^T single product
      f32x4 sfr[4];
#pragma unroll
      for (int nf=0;nf<4;nf++) sfr[nf] = fzero();
#pragma unroll
      for (int kk=0; kk<2; kk++){
        int kc = kk*4 + lg;
#pragma unroll
        for (int nf=0; nf<4; nf++){
          int r = nf*16 + li;
          bf16x8 bh_ = *(const bf16x8*)&khi_lds[r*64 + ((kc ^ (r & 7))*8)];
          sfr[nf] = mfma16(qfh[rf][kk], bh_, sfr[nf]);
        }
      }
      us* pl = &p_lds[w][0];
      if (far){
        float cq[4];
#pragma unroll
        for (int j=0;j<4;j++){
          int qloc = rf*64 + w*16 + lg*4 + j;
          cq[j] = b2f(c2p_lds[qloc*72 + cidx]);
        }
#pragma unroll
        for (int nf=0; nf<4; nf++){
          int col = nf*16 + li;
#pragma unroll
          for (int j=0;j<4;j++){
            float p = mk[nf] ? 0.f : exp2f(fmaf(sfr[nf][j], QS2, cq[j] + ckr[nf]));
            lrow[rf][j] += p;
            int row = lg*4 + j;
            pl[row*64 + ((col & 7) | ((((col >> 3) ^ (row & 7))) << 3))] = f2bf(p);
          }
        }
      } else {
#pragma unroll
        for (int nf=0; nf<4; nf++){
          int kloc = nf*16 + li;
          int col = kloc;
          int dbase = (q0 + rf*64 + w*16 + lg*4) - (k0 + kloc) + 1023;
          unsigned int iv;
          __builtin_memcpy(&iv, idxt + dbase, 4);   // idx for j=0..3 (packed bytes)
#pragma unroll
          for (int j=0;j<4;j++){
            int qloc = rf*64 + w*16 + lg*4 + j;
            int idx = (int)((iv >> (8*j)) & 0xff);
            float s2 = fmaf(sfr[nf][j], QS2,
                            b2f(c2p_lds[qloc*72 + idx]) + b2f(p2c_lds[kloc*72 + idx]));
            float p = mk[nf] ? 0.f : exp2f(s2);
            lrow[rf][j] += p;
            int row = lg*4 + j;
            pl[row*64 + ((col & 7) | ((((col >> 3) ^ (row & 7))) << 3))] = f2bf(p);
          }
        }
      }
      // PV single product (p_lds wave-private; same-wave DS ordering)
#pragma unroll
      for (int kk=0;kk<2;kk++){
        int kc = kk*4 + lg;
        bf16x8 af = *(const bf16x8*)((char*)pl + li*128 + ((kc ^ (li & 7)) * 16));
#pragma unroll
        for (int nf=0;nf<4;nf++){
          int r = nf*16 + li;
          bf16x8 bh_ = *(const bf16x8*)&vhi_lds[r*64 + ((kc ^ (r & 7))*8)];
          accO[rf][nf] = mfma16(af, bh_, accO[rf][nf]);
        }
      }
    }
  }

#pragma unroll
  for (int rf=0;rf<2;rf++)
    for (int o=1;o<16;o<<=1)
#pragma unroll
      for (int j=0;j<4;j++)
        lrow[rf][j] += __shfl_xor(lrow[rf][j], o);
#pragma unroll
  for (int rf=0;rf<2;rf++)
#pragma unroll
    for (int nf=0;nf<4;nf++)
#pragma unroll
      for (int j=0;j<4;j++){
        int qloc = rf*64 + w*16 + lg*4 + j;
        float o = accO[rf][nf][j] / lrow[rf][j];
        size_t idx = ((size_t)(b*1024 + q0 + qloc))*1024 + h*64 + nf*16 + li;
        us hh,ll; split2(o,hh,ll);
        ctx_hi[idx] = hh; ctx_lo[idx] = ll;
      }
}

// ---------------- launch ----------------
extern "C" void kernel_launch(void* const* d_in, const int* in_sizes, int n_in,
                              void* d_out, int out_size, void* d_ws, size_t ws_size,
                              hipStream_t stream)
{
  (void)in_sizes; (void)n_in; (void)out_size; (void)ws_size;
  const float* query = (const float*)d_in[0];
  const float* kvst  = (const float*)d_in[1];
  const unsigned char* mask = (const unsigned char*)d_in[2];
  const float* Wq = (const float*)d_in[3];  const float* bq = (const float*)d_in[4];
  const float* Wk = (const float*)d_in[5];  const float* bk = (const float*)d_in[6];
  const float* Wv = (const float*)d_in[7];  const float* bv = (const float*)d_in[8];
  const float* Wo = (const float*)d_in[9];  const float* bo = (const float*)d_in[10];
  const float* rel = (const float*)d_in[11];
  const float* lng = (const float*)d_in[12]; const float* lnb = (const float*)d_in[13];
  const float* Wpk = (const float*)d_in[14]; const float* bpk = (const float*)d_in[15];
  const float* Wpq = (const float*)d_in[16]; const float* bpq = (const float*)d_in[17];

  char* ws = (char*)d_ws;
  const size_t MB = 1024*1024;
  // layout (alias-safe by execution order):
  us* Xq_hi  = (us*)(ws + 0);        // dead after k_qkv
  us* p2c    = (us*)(ws + 8*MB);     // written by k_cp (after k_qkv)
  us* Xkv_hi = (us*)(ws + 16*MB);    // dead after k_qkv
  us* c2p    = (us*)(ws + 16*MB);    // written by k_cp
  us* vtb_hi = (us*)(ws + 24*MB);    // written by k_qkv (V class)
  us* Wt     = (us*)(ws + 32*MB);    // 6 slots x 4MB (hi 2MB + lo 2MB)
  us* ctx_hi = (us*)(ws + 32*MB);    // over Wq/Wk slots (dead after k_qkv)
  us* ctx_lo = (us*)(ws + 40*MB);    // over Wv/Wpk slots (dead after k_qkv/k_pos)
  us* reln_hi = (us*)(ws + 56*MB);
  us* posk_hi = (us*)(ws + 56*MB + 256*1024);
  us* posq_hi = (us*)(ws + 56*MB + 512*1024);
  signed char* idxt = (signed char*)(ws + 56*MB + 768*1024);
  us* qbuf_hi = (us*)(ws + 57*MB);
  us* kbuf_hi = (us*)(ws + 65*MB);

  k_convx<<<8192, 256, 0, stream>>>(query, kvst, Xq_hi, Xkv_hi);
  k_convw<<<dim3(32,32,6), 256, 0, stream>>>(Wq, Wk, Wv, Wpk, Wpq, Wo, Wt);
  k_lnrel<<<64, 256, 0, stream>>>(rel, lng, lnb, reln_hi);
  k_bucket<<<9, 256, 0, stream>>>(idxt);

  // pos FIRST (frees Wpk/Wpq slots before ctx aliases them)
  k_pos<<<dim3(16,2), 256, 0, stream>>>(reln_hi, Wt, bpk, bpq, posk_hi, posq_hi);

  k_qkv<<<1536, 256, 0, stream>>>(Xq_hi, Xkv_hi, Wt, bq, bk, bv, qbuf_hi, kbuf_hi, vtb_hi);

  k_cp<<<dim3(16,64,2), 256, 0, stream>>>(qbuf_hi, kbuf_hi, posk_hi, posq_hi, c2p, p2c);

  k_attn<<<dim3(8,64), 256, 0, stream>>>(qbuf_hi, kbuf_hi, vtb_hi,
                                         c2p, p2c, idxt, mask, ctx_hi, ctx_lo);

  k_gemmo<<<512, 256, 0, stream>>>(ctx_hi, ctx_lo, Wt + 5*2097152, Wt + 5*2097152 + 1048576, bo, (float*)d_out);
}

// Round 7
// 239.621 us; speedup vs baseline: 1.6842x; 1.6842x over previous
//
#include <hip/hip_runtime.h>
#include <cstdint>
#include <math.h>

typedef unsigned short us;
typedef __attribute__((ext_vector_type(8))) __bf16 bf16x8;
typedef __attribute__((ext_vector_type(8))) unsigned short ushort8;
typedef __attribute__((ext_vector_type(4))) float f32x4;

__device__ __forceinline__ us f2bf(float x){
  union { float f; unsigned int u; } v; v.f = x;
  unsigned int r = v.u + 0x7FFFu + ((v.u >> 16) & 1u);   // RNE
  return (us)(r >> 16);
}
__device__ __forceinline__ float b2f(us u){
  union { unsigned int u; float f; } v; v.u = ((unsigned int)u) << 16; return v.f;
}
__device__ __forceinline__ void split2(float x, us& hi, us& lo){
  hi = f2bf(x); lo = f2bf(x - b2f(hi));
}
__device__ __forceinline__ f32x4 fzero(){ f32x4 v; v.x=0.f; v.y=0.f; v.z=0.f; v.w=0.f; return v; }
__device__ __forceinline__ f32x4 mfma16(bf16x8 a, bf16x8 b, f32x4 c){
  return __builtin_amdgcn_mfma_f32_16x16x32_bf16(a, b, c, 0, 0, 0);
}
__device__ __forceinline__ void gload_lds16(const void* g, void* l){
  __builtin_amdgcn_global_load_lds(
      (const __attribute__((address_space(1))) unsigned int*)(uintptr_t)g,
      (__attribute__((address_space(3))) unsigned int*)(uintptr_t)l,
      16, 0, 0);
}

// exp2-folded scales
#define QS2 (0.07216878364870322f * 1.4426950408889634f)   // 1/sqrt(192) * log2(e)
#define BS  (0.08838834764831845f * 1.4426950408889634f)   // 1/sqrt(128) * log2(e)

// ---------------- 1: fused prep: convx | convw | lnrel | bucket ----------------
// blocks [0,8192): x->bf16 ; [8192,14336): W transpose+split ; [14336,14400): LN(rel) ; [14400,14409): bucket
__global__ __launch_bounds__(256) void k_prep(const float* __restrict__ xq,
                                              const float* __restrict__ xkv,
                                              const float* __restrict__ w0, const float* __restrict__ w1,
                                              const float* __restrict__ w2, const float* __restrict__ w3,
                                              const float* __restrict__ w4, const float* __restrict__ w5,
                                              const float* __restrict__ rel,
                                              const float* __restrict__ g, const float* __restrict__ bLN,
                                              us* __restrict__ qhi, us* __restrict__ kvhi,
                                              us* __restrict__ wt, us* __restrict__ reln_hi,
                                              signed char* __restrict__ idxt)
{
  __shared__ float tile[32][33];
  __shared__ float sm[8];
  const int bid = blockIdx.x, t = threadIdx.x;

  if (bid < 8192){                      // ---- convx (hi only)
    int i = bid * 256 + t;
    const float* src; us* dh;
    if (i < 1048576){ src = xq  + (size_t)i*4;           dh = qhi  + (size_t)i*4; }
    else            { src = xkv + (size_t)(i-1048576)*4; dh = kvhi + (size_t)(i-1048576)*4; }
    f32x4 v = *(const f32x4*)src;
    dh[0]=f2bf(v.x); dh[1]=f2bf(v.y); dh[2]=f2bf(v.z); dh[3]=f2bf(v.w);
    return;
  }
  if (bid < 14336){                     // ---- convw: transpose + hi/lo split
    int rem = bid - 8192;
    int z = rem >> 10, r2 = rem & 1023;
    const float* W = (z==0)?w0:(z==1)?w1:(z==2)?w2:(z==3)?w3:(z==4)?w4:w5;
    us* dst_hi = wt + (size_t)z * 2097152;
    us* dst_lo = dst_hi + 1048576;
    bool wlo = (z == 2) || (z == 5);
    int n0 = (r2 & 31) * 32, k0 = (r2 >> 5) * 32;
    int c = t & 31, r = t >> 5;
#pragma unroll
    for (int i = 0; i < 4; i++)
      tile[r + i*8][c] = W[(size_t)(k0 + r + i*8)*1024 + n0 + c];
    __syncthreads();
#pragma unroll
    for (int i = 0; i < 4; i++){
      int nn = r + i*8;
      us h,l; split2(tile[c][nn], h, l);
      dst_hi[(size_t)(n0 + nn)*1024 + k0 + c] = h;
      if (wlo) dst_lo[(size_t)(n0 + nn)*1024 + k0 + c] = l;
    }
    return;
  }
  if (bid < 14400){                     // ---- lnrel
    int row = bid - 14336;
    const float* x = rel + (size_t)row * 1024;
    float v[4]; float s = 0.f, ss = 0.f;
#pragma unroll
    for (int i=0;i<4;i++){ v[i] = x[t + 256*i]; s += v[i]; ss += v[i]*v[i]; }
    for (int o=32;o;o>>=1){ s += __shfl_xor(s,o); ss += __shfl_xor(ss,o); }
    int w = t >> 6;
    if ((t & 63) == 0){ sm[w] = s; sm[4+w] = ss; }
    __syncthreads();
    s  = sm[0]+sm[1]+sm[2]+sm[3];
    ss = sm[4]+sm[5]+sm[6]+sm[7];
    float mu  = s  * (1.0f/1024.0f);
    float var = ss * (1.0f/1024.0f) - mu*mu;
    float rs  = rsqrtf(var + 1e-5f);
#pragma unroll
    for (int i=0;i<4;i++){
      int cc = t + 256*i;
      reln_hi[(size_t)row*1024 + cc] = f2bf((v[i]-mu)*rs*g[cc] + bLN[cc]);
    }
    return;
  }
  {                                     // ---- bucket table
    int i = (bid - 14400) * 256 + t;
    if (i >= 2052) return;
    int d = i - 1023;
    int ad = d < 0 ? -d : d;
    int abspos = (d < 16 && d > -16) ? 15 : ad;
    int bucket;
    if (abspos <= 16) bucket = d;
    else {
      float num = (float)log((double)abspos * 0.0625);
      float den = (float)log(7.9375);
      float lp = ceilf(num / den * 15.0f) + 16.0f;
      bucket = (int)lp * (d > 0 ? 1 : -1);
    }
    int s = bucket + 32;
    s = s < 0 ? 0 : (s > 63 ? 63 : s);
    idxt[i] = (signed char)s;
  }
}

// ---------------- 2: merged QKV GEMM + pos projections ----------------
// blocks [0,1536): cls 0 Q (NKT 32), cls 1 K (NKT 32), cls 2 V (NKT 64, out [B,H,HD,T])
// blocks [1536,1568): pos_k / pos_q (single product)
__global__ __launch_bounds__(256, 4) void k_qkvp(const us* __restrict__ Xq, const us* __restrict__ Xkv,
                                                 const us* __restrict__ wt,
                                                 const float* __restrict__ bq, const float* __restrict__ bk,
                                                 const float* __restrict__ bv,
                                                 const us* __restrict__ reln_hi,
                                                 const float* __restrict__ bpk, const float* __restrict__ bpq,
                                                 us* __restrict__ qbuf, us* __restrict__ kbuf,
                                                 us* __restrict__ vtb,
                                                 us* __restrict__ posk_hi, us* __restrict__ posq_hi)
{
  __shared__ __align__(16) us a_lds[2][4096];   // 128 x 32
  __shared__ __align__(16) us b_lds[2][2048];   // 64 x 32
  const int bid = blockIdx.x;
  const int t = threadIdx.x, w = t >> 6, lane = t & 63, lg = lane >> 4, li = lane & 15;

  if (bid >= 1536){                     // ---- pos projections
    int wg2 = bid - 1536;
    int ntile = wg2 & 15, z = wg2 >> 4;
    const us* W_hi = wt + (size_t)(3 + z) * 2097152;
    const float* bias = z ? bpq : bpk;
    us* out_hi = z ? posq_hi : posk_hi;
    f32x4 acc[4];
#pragma unroll
    for (int i=0;i<4;i++) acc[i] = fzero();
    int srow = w*16 + li;
    for (int kt = 0; kt < 32; kt++){
      int k0 = kt*32 + lg*8;
      bf16x8 a = *(const bf16x8*)(reln_hi + (size_t)srow*1024 + k0);
#pragma unroll
      for (int nf=0; nf<4; nf++){
        int n = ntile*64 + nf*16 + li;
        bf16x8 b = *(const bf16x8*)(W_hi + (size_t)n*1024 + k0);
        acc[nf] = mfma16(a, b, acc[nf]);
      }
    }
#pragma unroll
    for (int nf=0;nf<4;nf++){
      int n = ntile*64 + nf*16 + li;
      float bn = bias[n];
      int h = n >> 6, hd = n & 63;
#pragma unroll
      for (int j=0;j<4;j++){
        int s = w*16 + lg*4 + j;
        out_hi[(size_t)h*4096 + s*64 + hd] = f2bf(acc[nf][j] + bn);
      }
    }
    return;
  }

  // ---- QKV classes
  int wg = (bid & 7) * 192 + (bid >> 3);        // XCD swizzle, 1536 % 8 == 0
  int cls = wg >> 9, tix = wg & 511;
  int mt = tix >> 4, nt = tix & 15;
  int m0 = mt * 128, n0 = nt * 64;
  const us* A  = (cls == 0) ? Xq : Xkv;
  const us* Bh = wt + (size_t)cls * 2097152;
  const us* Bl = Bh + 1048576;
  const float* bias = (cls==0) ? bq : (cls==1) ? bk : bv;
  const int NKT = (cls == 2) ? 64 : 32;
  int wm = w >> 1, wn = w & 1;
  f32x4 acc[4][2];
#pragma unroll
  for (int i=0;i<4;i++){ acc[i][0]=fzero(); acc[i][1]=fzero(); }

  auto stage = [&](int buf, int kt){
    int seg = kt >> 5, k0 = (kt & 31) * 32;
    const us* Bp = seg ? Bl : Bh;
#pragma unroll
    for (int c = 0; c < 2; c++){
      int slot = c*256 + t;
      int g = slot ^ ((slot >> 3) & 7);
      int r = g >> 2, kc = g & 3;
      gload_lds16(A + (size_t)(m0 + r)*1024 + k0 + kc*8, (char*)&a_lds[buf][0] + slot*16);
    }
    {
      int slot = t;
      int g = slot ^ ((slot >> 3) & 7);
      int r = g >> 2, kc = g & 3;
      gload_lds16(Bp + (size_t)(n0 + r)*1024 + k0 + kc*8, (char*)&b_lds[buf][0] + slot*16);
    }
  };

  stage(0, 0);
  __syncthreads();
  int buf = 0;
  for (int kt = 0; kt < NKT; kt++){
    if (kt + 1 < NKT) stage(buf ^ 1, kt + 1);
    bf16x8 af[4], bfv[2];
#pragma unroll
    for (int mi=0;mi<4;mi++){
      int r = wm*64 + mi*16 + li;
      int s = (r*4 + lg); s ^= ((s >> 3) & 7);
      af[mi] = *(const bf16x8*)((char*)&a_lds[buf][0] + s*16);
    }
#pragma unroll
    for (int ni=0;ni<2;ni++){
      int r = wn*32 + ni*16 + li;
      int s = (r*4 + lg); s ^= ((s >> 3) & 7);
      bfv[ni] = *(const bf16x8*)((char*)&b_lds[buf][0] + s*16);
    }
#pragma unroll
    for (int mi=0;mi<4;mi++)
#pragma unroll
      for (int ni=0;ni<2;ni++)
        acc[mi][ni] = mfma16(af[mi], bfv[ni], acc[mi][ni]);
    __syncthreads();
    buf ^= 1;
  }

#pragma unroll
  for (int ni=0;ni<2;ni++){
    int n = n0 + wn*32 + ni*16 + li;
    float bn = bias[n];
    int hh = n >> 6, hd = n & 63;
#pragma unroll
    for (int mi=0;mi<4;mi++){
      int mb = m0 + wm*64 + mi*16 + lg*4;
#pragma unroll
      for (int j=0;j<4;j++){
        int m = mb + j;
        float val = acc[mi][ni][j] + bn;
        int bb = m >> 10, tp = m & 1023;
        if (cls == 2)
          vtb[(((size_t)(bb*16 + hh))*64 + hd)*1024 + tp] = f2bf(val);
        else {
          us* out = cls ? kbuf : qbuf;
          out[(((size_t)(bb*16 + hh))*1024 + tp)*64 + hd] = f2bf(val);
        }
      }
    }
  }
}

// ---------------- 3: O GEMM: 3 products, BM=128, BN=64, fp32 out ----------------
__global__ __launch_bounds__(256, 2) void k_gemmo(const us* __restrict__ A_hi, const us* __restrict__ A_lo,
                                                  const us* __restrict__ B_hi, const us* __restrict__ B_lo,
                                                  const float* __restrict__ bias,
                                                  float* __restrict__ out_f)
{
  __shared__ __align__(16) us a_lds[2][4096];
  __shared__ __align__(16) us b_lds[2][2048];
  int bid = blockIdx.x;
  int wg = (bid & 7) * 64 + (bid >> 3);        // 512 % 8 == 0
  int mt = wg >> 4, nt = wg & 15;
  int m0 = mt * 128, n0 = nt * 64;
  int t = threadIdx.x, w = t >> 6, lane = t & 63, lg = lane >> 4, li = lane & 15;
  int wm = w >> 1, wn = w & 1;
  f32x4 acc[4][2];
#pragma unroll
  for (int i=0;i<4;i++){ acc[i][0]=fzero(); acc[i][1]=fzero(); }

  auto stage = [&](int buf, int kt){
    int seg = kt >> 5, k0 = (kt & 31) * 32;
    const us* Ap = (seg == 2) ? A_lo : A_hi;
    const us* Bp = (seg == 1) ? B_lo : B_hi;
#pragma unroll
    for (int c = 0; c < 2; c++){
      int slot = c*256 + t;
      int g = slot ^ ((slot >> 3) & 7);
      int r = g >> 2, kc = g & 3;
      gload_lds16(Ap + (size_t)(m0 + r)*1024 + k0 + kc*8, (char*)&a_lds[buf][0] + slot*16);
    }
    {
      int slot = t;
      int g = slot ^ ((slot >> 3) & 7);
      int r = g >> 2, kc = g & 3;
      gload_lds16(Bp + (size_t)(n0 + r)*1024 + k0 + kc*8, (char*)&b_lds[buf][0] + slot*16);
    }
  };

  stage(0, 0);
  __syncthreads();
  int buf = 0;
  for (int kt = 0; kt < 96; kt++){
    if (kt + 1 < 96) stage(buf ^ 1, kt + 1);
    bf16x8 af[4], bfv[2];
#pragma unroll
    for (int mi=0;mi<4;mi++){
      int r = wm*64 + mi*16 + li;
      int s = (r*4 + lg); s ^= ((s >> 3) & 7);
      af[mi] = *(const bf16x8*)((char*)&a_lds[buf][0] + s*16);
    }
#pragma unroll
    for (int ni=0;ni<2;ni++){
      int r = wn*32 + ni*16 + li;
      int s = (r*4 + lg); s ^= ((s >> 3) & 7);
      bfv[ni] = *(const bf16x8*)((char*)&b_lds[buf][0] + s*16);
    }
#pragma unroll
    for (int mi=0;mi<4;mi++)
#pragma unroll
      for (int ni=0;ni<2;ni++)
        acc[mi][ni] = mfma16(af[mi], bfv[ni], acc[mi][ni]);
    __syncthreads();
    buf ^= 1;
  }

#pragma unroll
  for (int ni=0;ni<2;ni++){
    int n = n0 + wn*32 + ni*16 + li;
    float bn = bias[n];
#pragma unroll
    for (int mi=0;mi<4;mi++){
      int mb = m0 + wm*64 + mi*16 + lg*4;
#pragma unroll
      for (int j=0;j<4;j++)
        out_f[(size_t)(mb + j)*1024 + n] = acc[mi][ni][j] + bn;
    }
  }
}

// ---------------- 4: c2p/p2c (single product, pre-scaled by BS for exp2) ----------------
__global__ __launch_bounds__(256) void k_cp(const us* __restrict__ q_hi,
                                            const us* __restrict__ k_hi,
                                            const us* __restrict__ pk_hi,
                                            const us* __restrict__ pq_hi,
                                            us* __restrict__ c2p, us* __restrict__ p2c)
{
  int qt = blockIdx.x, bh = blockIdx.y, z = blockIdx.z;
  const us* X_hi = z ? k_hi : q_hi;
  const us* P_hi = z ? pq_hi : pk_hi;
  us* out = z ? p2c : c2p;
  int h = bh & 15;
  int t = threadIdx.x, w = t >> 6, lane = t & 63, lg = lane >> 4, li = lane & 15;
  f32x4 acc[4];
#pragma unroll
  for (int i=0;i<4;i++) acc[i] = fzero();
  size_t row = (size_t)bh*1024 + qt*64 + w*16 + li;
#pragma unroll
  for (int kk=0;kk<2;kk++){
    int k = kk*32 + lg*8;
    bf16x8 ah = *(const bf16x8*)(X_hi + row*64 + k);
#pragma unroll
    for (int nf=0;nf<4;nf++){
      int s = nf*16 + li;
      bf16x8 bh_ = *(const bf16x8*)(P_hi + (size_t)h*4096 + s*64 + k);
      acc[nf] = mfma16(ah, bh_, acc[nf]);
    }
  }
  size_t obase = ((size_t)bh*1024 + qt*64 + w*16 + lg*4) * 64;
#pragma unroll
  for (int nf=0;nf<4;nf++)
#pragma unroll
    for (int j=0;j<4;j++)
      out[obase + (size_t)j*64 + nf*16 + li] = f2bf(acc[nf][j] * BS);
}

// ---------------- 5: fused attention: 8 waves, QBLK=128, far fast path (r5 version) ----------------
__global__ __launch_bounds__(512) void k_attn(const us* __restrict__ qhi,
                                              const us* __restrict__ khi,
                                              const us* __restrict__ vhi,
                                              const us* __restrict__ c2p, const us* __restrict__ p2c,
                                              const signed char* __restrict__ idxt,
                                              const unsigned char* __restrict__ mask,
                                              us* __restrict__ ctx_hi, us* __restrict__ ctx_lo)
{
  __shared__ __align__(16) us khi_lds[4096], vhi_lds[4096];
  __shared__ __align__(16) us c2p_lds[128*72], p2c_lds[64*72];   // padded rows: 144B stride
  __shared__ __align__(16) us p_lds[8][1024];
  __shared__ signed char idx_lds[2048];

  const int qt = blockIdx.x, bh = blockIdx.y;   // qt: 0..7
  const int b = bh >> 4, h = bh & 15;
  const int t = threadIdx.x, w = t >> 6, lane = t & 63, lg = lane >> 4, li = lane & 15;
  const int q0 = qt * 128;

  for (int i = t; i < 2047; i += 512) idx_lds[i] = idxt[i];
  {
    const us* src = c2p + ((size_t)bh*1024 + q0) * 64;
#pragma unroll
    for (int c = 0; c < 2; c++){
      int f = c*512 + t, r = f >> 3, kc = f & 7;
      *(ushort8*)&c2p_lds[r*72 + kc*8] = *(const ushort8*)(src + r*64 + kc*8);
    }
  }
  bf16x8 qfh[2];
  {
    const us* qph = qhi + ((size_t)bh*1024 + q0 + w*16 + li)*64 + lg*8;
    qfh[0] = *(const bf16x8*)(qph); qfh[1] = *(const bf16x8*)(qph + 32);
  }
  __syncthreads();
  // far-path per-row bias (scaled) for idx=0 / idx=63
  float cq0[4], cq63[4];
#pragma unroll
  for (int j=0;j<4;j++){
    int qloc = w*16 + lg*4 + j;
    cq0[j]  = b2f(c2p_lds[qloc*72 + 0]);
    cq63[j] = b2f(c2p_lds[qloc*72 + 63]);
  }

  float lrow[4];
  f32x4 accO[4];
#pragma unroll
  for (int j=0;j<4;j++){ lrow[j] = 0.f; accO[j] = fzero(); }
  const unsigned char* mptr = mask + b*1024;

  for (int kt = 0; kt < 16; kt++){
    const int k0 = kt * 64;
    const bool far = (q0 - k0 >= 192) || (k0 - q0 >= 256);
    __syncthreads();
    {  // stage K,V: one 16B chunk each per thread
      int r = t >> 3, kc = t & 7;
      *(ushort8*)&khi_lds[r*64 + ((kc ^ (r & 7))*8)] =
          *(const ushort8*)(khi + ((size_t)bh*1024 + k0 + r)*64 + kc*8);
      *(ushort8*)&vhi_lds[r*64 + ((kc ^ (r & 7))*8)] =
          *(const ushort8*)(vhi + ((size_t)bh*64 + r)*1024 + k0 + kc*8);
      if (!far)
        *(ushort8*)&p2c_lds[r*72 + kc*8] =
            *(const ushort8*)(p2c + ((size_t)bh*1024 + k0 + r)*64 + kc*8);
    }
    __syncthreads();

    // QK^T single product
    f32x4 sfr[4];
#pragma unroll
    for (int nf=0;nf<4;nf++) sfr[nf] = fzero();
#pragma unroll
    for (int kk=0; kk<2; kk++){
      int kc = kk*4 + lg;
#pragma unroll
      for (int nf=0; nf<4; nf++){
        int r = nf*16 + li;
        bf16x8 bh_ = *(const bf16x8*)&khi_lds[r*64 + ((kc ^ (r & 7))*8)];
        sfr[nf] = mfma16(qfh[kk], bh_, sfr[nf]);
      }
    }
    us* pl = &p_lds[w][0];
    if (far){
      const int cidx = (q0 > k0) ? 63 : 0;
      float cq[4];
#pragma unroll
      for (int j=0;j<4;j++) cq[j] = (q0 > k0) ? cq63[j] : cq0[j];
#pragma unroll
      for (int nf=0; nf<4; nf++){
        int kloc = nf*16 + li;
        bool mk = mptr[k0 + kloc] != 0;
        float ck = b2f(p2c[((size_t)bh*1024 + k0 + kloc)*64 + cidx]);
        int col = kloc;
#pragma unroll
        for (int j=0;j<4;j++){
          float p = mk ? 0.f : exp2f(fmaf(sfr[nf][j], QS2, cq[j] + ck));
          lrow[j] += p;
          int row = lg*4 + j;
          pl[row*64 + ((col & 7) | ((((col >> 3) ^ (row & 7))) << 3))] = f2bf(p);
        }
      }
    } else {
#pragma unroll
      for (int nf=0; nf<4; nf++){
        int kloc = nf*16 + li;
        bool mk = mptr[k0 + kloc] != 0;
        int col = kloc;
#pragma unroll
        for (int j=0;j<4;j++){
          int qloc = w*16 + lg*4 + j;
          int d = (q0 + qloc) - (k0 + kloc);
          int idx = (int)idx_lds[d + 1023];
          float s2 = fmaf(sfr[nf][j], QS2,
                          b2f(c2p_lds[qloc*72 + idx]) + b2f(p2c_lds[kloc*72 + idx]));
          float p = mk ? 0.f : exp2f(s2);
          lrow[j] += p;
          int row = lg*4 + j;
          pl[row*64 + ((col & 7) | ((((col >> 3) ^ (row & 7))) << 3))] = f2bf(p);
        }
      }
    }
    // PV single product (p_lds wave-private; same-wave DS ordering)
#pragma unroll
    for (int kk=0;kk<2;kk++){
      int kc = kk*4 + lg;
      bf16x8 af = *(const bf16x8*)((char*)pl + li*128 + ((kc ^ (li & 7)) * 16));
#pragma unroll
      for (int nf=0;nf<4;nf++){
        int r = nf*16 + li;
        bf16x8 bh_ = *(const bf16x8*)&vhi_lds[r*64 + ((kc ^ (r & 7))*8)];
        accO[nf] = mfma16(af, bh_, accO[nf]);
      }
    }
  }

  for (int o=1;o<16;o<<=1)
#pragma unroll
    for (int j=0;j<4;j++)
      lrow[j] += __shfl_xor(lrow[j], o);
#pragma unroll
  for (int nf=0;nf<4;nf++)
#pragma unroll
    for (int j=0;j<4;j++){
      int qloc = w*16 + lg*4 + j;
      float o = accO[nf][j] / lrow[j];
      size_t idx = ((size_t)(b*1024 + q0 + qloc))*1024 + h*64 + nf*16 + li;
      us hh,ll; split2(o,hh,ll);
      ctx_hi[idx] = hh; ctx_lo[idx] = ll;
    }
}

// ---------------- launch ----------------
extern "C" void kernel_launch(void* const* d_in, const int* in_sizes, int n_in,
                              void* d_out, int out_size, void* d_ws, size_t ws_size,
                              hipStream_t stream)
{
  (void)in_sizes; (void)n_in; (void)out_size; (void)ws_size;
  const float* query = (const float*)d_in[0];
  const float* kvst  = (const float*)d_in[1];
  const unsigned char* mask = (const unsigned char*)d_in[2];
  const float* Wq = (const float*)d_in[3];  const float* bq = (const float*)d_in[4];
  const float* Wk = (const float*)d_in[5];  const float* bk = (const float*)d_in[6];
  const float* Wv = (const float*)d_in[7];  const float* bv = (const float*)d_in[8];
  const float* Wo = (const float*)d_in[9];  const float* bo = (const float*)d_in[10];
  const float* rel = (const float*)d_in[11];
  const float* lng = (const float*)d_in[12]; const float* lnb = (const float*)d_in[13];
  const float* Wpk = (const float*)d_in[14]; const float* bpk = (const float*)d_in[15];
  const float* Wpq = (const float*)d_in[16]; const float* bpq = (const float*)d_in[17];

  char* ws = (char*)d_ws;
  const size_t MB = 1024*1024;
  // layout (alias-safe by execution order):
  us* Xq_hi  = (us*)(ws + 0);        // dead after k_qkvp
  us* p2c    = (us*)(ws + 8*MB);     // written by k_cp (after k_qkvp)
  us* Xkv_hi = (us*)(ws + 16*MB);    // dead after k_qkvp
  us* c2p    = (us*)(ws + 16*MB);    // written by k_cp
  us* vtb_hi = (us*)(ws + 24*MB);    // written by k_qkvp (V class)
  us* Wt     = (us*)(ws + 32*MB);    // 6 slots x 4MB (hi 2MB + lo 2MB)
  us* ctx_hi = (us*)(ws + 32*MB);    // over Wq/Wk slots (dead after k_qkvp)
  us* ctx_lo = (us*)(ws + 40*MB);    // over Wv/Wpk slots (dead after k_qkvp)
  us* reln_hi = (us*)(ws + 56*MB);
  us* posk_hi = (us*)(ws + 56*MB + 256*1024);
  us* posq_hi = (us*)(ws + 56*MB + 512*1024);
  signed char* idxt = (signed char*)(ws + 56*MB + 768*1024);
  us* qbuf_hi = (us*)(ws + 57*MB);
  us* kbuf_hi = (us*)(ws + 65*MB);

  k_prep<<<14409, 256, 0, stream>>>(query, kvst, Wq, Wk, Wv, Wpk, Wpq, Wo,
                                    rel, lng, lnb,
                                    Xq_hi, Xkv_hi, Wt, reln_hi, idxt);

  k_qkvp<<<1568, 256, 0, stream>>>(Xq_hi, Xkv_hi, Wt, bq, bk, bv,
                                   reln_hi, bpk, bpq,
                                   qbuf_hi, kbuf_hi, vtb_hi, posk_hi, posq_hi);

  k_cp<<<dim3(16,64,2), 256, 0, stream>>>(qbuf_hi, kbuf_hi, posk_hi, posq_hi, c2p, p2c);

  k_attn<<<dim3(8,64), 512, 0, stream>>>(qbuf_hi, kbuf_hi, vtb_hi,
                                         c2p, p2c, idxt, mask, ctx_hi, ctx_lo);

  k_gemmo<<<512, 256, 0, stream>>>(ctx_hi, ctx_lo, Wt + 5*2097152, Wt + 5*2097152 + 1048576, bo, (float*)d_out);
}

// Round 8
// 228.019 us; speedup vs baseline: 1.7698x; 1.0509x over previous
//
#include <hip/hip_runtime.h>
#include <cstdint>
#include <math.h>

typedef unsigned short us;
typedef __attribute__((ext_vector_type(8))) __bf16 bf16x8;
typedef __attribute__((ext_vector_type(8))) unsigned short ushort8;
typedef __attribute__((ext_vector_type(4))) float f32x4;

__device__ __forceinline__ us f2bf(float x){
  union { float f; unsigned int u; } v; v.f = x;
  unsigned int r = v.u + 0x7FFFu + ((v.u >> 16) & 1u);   // RNE
  return (us)(r >> 16);
}
__device__ __forceinline__ float b2f(us u){
  union { unsigned int u; float f; } v; v.u = ((unsigned int)u) << 16; return v.f;
}
__device__ __forceinline__ void split2(float x, us& hi, us& lo){
  hi = f2bf(x); lo = f2bf(x - b2f(hi));
}
__device__ __forceinline__ f32x4 fzero(){ f32x4 v; v.x=0.f; v.y=0.f; v.z=0.f; v.w=0.f; return v; }
__device__ __forceinline__ f32x4 mfma16(bf16x8 a, bf16x8 b, f32x4 c){
  return __builtin_amdgcn_mfma_f32_16x16x32_bf16(a, b, c, 0, 0, 0);
}
__device__ __forceinline__ void gload_lds16(const void* g, void* l){
  __builtin_amdgcn_global_load_lds(
      (const __attribute__((address_space(1))) unsigned int*)(uintptr_t)g,
      (__attribute__((address_space(3))) unsigned int*)(uintptr_t)l,
      16, 0, 0);
}

// exp2-folded scales
#define QS2 (0.07216878364870322f * 1.4426950408889634f)   // 1/sqrt(192) * log2(e)
#define BS  (0.08838834764831845f * 1.4426950408889634f)   // 1/sqrt(128) * log2(e)

// ---------------- 1: fused prep: convx | convw | lnrel | bucket ----------------
__global__ __launch_bounds__(256) void k_prep(const float* __restrict__ xq,
                                              const float* __restrict__ xkv,
                                              const float* __restrict__ w0, const float* __restrict__ w1,
                                              const float* __restrict__ w2, const float* __restrict__ w3,
                                              const float* __restrict__ w4, const float* __restrict__ w5,
                                              const float* __restrict__ rel,
                                              const float* __restrict__ g, const float* __restrict__ bLN,
                                              us* __restrict__ qhi, us* __restrict__ kvhi,
                                              us* __restrict__ wt, us* __restrict__ reln_hi,
                                              signed char* __restrict__ idxt)
{
  __shared__ float tile[32][33];
  __shared__ float sm[8];
  const int bid = blockIdx.x, t = threadIdx.x;

  if (bid < 8192){                      // ---- convx (hi only)
    int i = bid * 256 + t;
    const float* src; us* dh;
    if (i < 1048576){ src = xq  + (size_t)i*4;           dh = qhi  + (size_t)i*4; }
    else            { src = xkv + (size_t)(i-1048576)*4; dh = kvhi + (size_t)(i-1048576)*4; }
    f32x4 v = *(const f32x4*)src;
    dh[0]=f2bf(v.x); dh[1]=f2bf(v.y); dh[2]=f2bf(v.z); dh[3]=f2bf(v.w);
    return;
  }
  if (bid < 14336){                     // ---- convw: transpose + hi/lo split
    int rem = bid - 8192;
    int z = rem >> 10, r2 = rem & 1023;
    const float* W = (z==0)?w0:(z==1)?w1:(z==2)?w2:(z==3)?w3:(z==4)?w4:w5;
    us* dst_hi = wt + (size_t)z * 2097152;
    us* dst_lo = dst_hi + 1048576;
    bool wlo = (z == 2) || (z == 5);
    int n0 = (r2 & 31) * 32, k0 = (r2 >> 5) * 32;
    int c = t & 31, r = t >> 5;
#pragma unroll
    for (int i = 0; i < 4; i++)
      tile[r + i*8][c] = W[(size_t)(k0 + r + i*8)*1024 + n0 + c];
    __syncthreads();
#pragma unroll
    for (int i = 0; i < 4; i++){
      int nn = r + i*8;
      us h,l; split2(tile[c][nn], h, l);
      dst_hi[(size_t)(n0 + nn)*1024 + k0 + c] = h;
      if (wlo) dst_lo[(size_t)(n0 + nn)*1024 + k0 + c] = l;
    }
    return;
  }
  if (bid < 14400){                     // ---- lnrel
    int row = bid - 14336;
    const float* x = rel + (size_t)row * 1024;
    float v[4]; float s = 0.f, ss = 0.f;
#pragma unroll
    for (int i=0;i<4;i++){ v[i] = x[t + 256*i]; s += v[i]; ss += v[i]*v[i]; }
    for (int o=32;o;o>>=1){ s += __shfl_xor(s,o); ss += __shfl_xor(ss,o); }
    int w = t >> 6;
    if ((t & 63) == 0){ sm[w] = s; sm[4+w] = ss; }
    __syncthreads();
    s  = sm[0]+sm[1]+sm[2]+sm[3];
    ss = sm[4]+sm[5]+sm[6]+sm[7];
    float mu  = s  * (1.0f/1024.0f);
    float var = ss * (1.0f/1024.0f) - mu*mu;
    float rs  = rsqrtf(var + 1e-5f);
#pragma unroll
    for (int i=0;i<4;i++){
      int cc = t + 256*i;
      reln_hi[(size_t)row*1024 + cc] = f2bf((v[i]-mu)*rs*g[cc] + bLN[cc]);
    }
    return;
  }
  {                                     // ---- bucket table
    int i = (bid - 14400) * 256 + t;
    if (i >= 2052) return;
    int d = i - 1023;
    int ad = d < 0 ? -d : d;
    int abspos = (d < 16 && d > -16) ? 15 : ad;
    int bucket;
    if (abspos <= 16) bucket = d;
    else {
      float num = (float)log((double)abspos * 0.0625);
      float den = (float)log(7.9375);
      float lp = ceilf(num / den * 15.0f) + 16.0f;
      bucket = (int)lp * (d > 0 ? 1 : -1);
    }
    int s = bucket + 32;
    s = s < 0 ? 0 : (s > 63 ? 63 : s);
    idxt[i] = (signed char)s;
  }
}

// ---------------- 2: merged QKV GEMM (BM=128, BN=128) + pos projections ----------------
// blocks [0,768): 256 each cls 0 Q (NKT 32), cls 1 K (NKT 32), cls 2 V (NKT 64, out [B,H,HD,T])
// blocks [768,800): pos_k / pos_q (single product)
__global__ __launch_bounds__(256) void k_qkvp(const us* __restrict__ Xq, const us* __restrict__ Xkv,
                                              const us* __restrict__ wt,
                                              const float* __restrict__ bq, const float* __restrict__ bk,
                                              const float* __restrict__ bv,
                                              const us* __restrict__ reln_hi,
                                              const float* __restrict__ bpk, const float* __restrict__ bpq,
                                              us* __restrict__ qbuf, us* __restrict__ kbuf,
                                              us* __restrict__ vtb,
                                              us* __restrict__ posk_hi, us* __restrict__ posq_hi)
{
  __shared__ __align__(16) us a_lds[2][4096];   // 128 x 32
  __shared__ __align__(16) us b_lds[2][4096];   // 128 x 32
  const int bid = blockIdx.x;
  const int t = threadIdx.x, w = t >> 6, lane = t & 63, lg = lane >> 4, li = lane & 15;

  if (bid >= 768){                      // ---- pos projections (32 blocks)
    int wg2 = bid - 768;
    int ntile = wg2 & 15, z = wg2 >> 4;
    const us* W_hi = wt + (size_t)(3 + z) * 2097152;
    const float* bias = z ? bpq : bpk;
    us* out_hi = z ? posq_hi : posk_hi;
    f32x4 acc[4];
#pragma unroll
    for (int i=0;i<4;i++) acc[i] = fzero();
    int srow = w*16 + li;
    for (int kt = 0; kt < 32; kt++){
      int k0 = kt*32 + lg*8;
      bf16x8 a = *(const bf16x8*)(reln_hi + (size_t)srow*1024 + k0);
#pragma unroll
      for (int nf=0; nf<4; nf++){
        int n = ntile*64 + nf*16 + li;
        bf16x8 b = *(const bf16x8*)(W_hi + (size_t)n*1024 + k0);
        acc[nf] = mfma16(a, b, acc[nf]);
      }
    }
#pragma unroll
    for (int nf=0;nf<4;nf++){
      int n = ntile*64 + nf*16 + li;
      float bn = bias[n];
      int h = n >> 6, hd = n & 63;
#pragma unroll
      for (int j=0;j<4;j++){
        int s = w*16 + lg*4 + j;
        out_hi[(size_t)h*4096 + s*64 + hd] = f2bf(acc[nf][j] + bn);
      }
    }
    return;
  }

  // ---- QKV classes, r5-proven geometry
  int wg = (bid & 7) * 96 + (bid >> 3);        // XCD swizzle, 768 % 8 == 0
  int cls = wg >> 8, tix = wg & 255;
  int mt = tix >> 3, nt = tix & 7;
  int m0 = mt * 128, n0 = nt * 128;
  const us* A  = (cls == 0) ? Xq : Xkv;
  const us* Bh = wt + (size_t)cls * 2097152;
  const us* Bl = Bh + 1048576;
  const float* bias = (cls==0) ? bq : (cls==1) ? bk : bv;
  const int NKT = (cls == 2) ? 64 : 32;
  int wm = w >> 1, wn = w & 1;
  f32x4 acc[4][4];
#pragma unroll
  for (int i=0;i<4;i++)
#pragma unroll
    for (int j=0;j<4;j++) acc[i][j] = fzero();

  auto stage = [&](int buf, int kt){
    int seg = kt >> 5, k0 = (kt & 31) * 32;
    const us* Bp = seg ? Bl : Bh;
#pragma unroll
    for (int c = 0; c < 2; c++){
      int slot = c*256 + t;
      int g = slot ^ ((slot >> 3) & 7);
      int r = g >> 2, kc = g & 3;
      gload_lds16(A  + (size_t)(m0 + r)*1024 + k0 + kc*8, (char*)&a_lds[buf][0] + slot*16);
      gload_lds16(Bp + (size_t)(n0 + r)*1024 + k0 + kc*8, (char*)&b_lds[buf][0] + slot*16);
    }
  };

  stage(0, 0);
  __syncthreads();
  int buf = 0;
  for (int kt = 0; kt < NKT; kt++){
    if (kt + 1 < NKT) stage(buf ^ 1, kt + 1);
    bf16x8 af[4], bfv[4];
#pragma unroll
    for (int mi=0;mi<4;mi++){
      int r = wm*64 + mi*16 + li;
      int s = (r*4 + lg); s ^= ((s >> 3) & 7);
      af[mi] = *(const bf16x8*)((char*)&a_lds[buf][0] + s*16);
    }
#pragma unroll
    for (int ni=0;ni<4;ni++){
      int r = wn*64 + ni*16 + li;
      int s = (r*4 + lg); s ^= ((s >> 3) & 7);
      bfv[ni] = *(const bf16x8*)((char*)&b_lds[buf][0] + s*16);
    }
#pragma unroll
    for (int mi=0;mi<4;mi++)
#pragma unroll
      for (int ni=0;ni<4;ni++)
        acc[mi][ni] = mfma16(af[mi], bfv[ni], acc[mi][ni]);
    __syncthreads();
    buf ^= 1;
  }

#pragma unroll
  for (int ni=0;ni<4;ni++){
    int n = n0 + wn*64 + ni*16 + li;
    float bn = bias[n];
    int hh = n >> 6, hd = n & 63;
#pragma unroll
    for (int mi=0;mi<4;mi++){
      int mb = m0 + wm*64 + mi*16 + lg*4;
#pragma unroll
      for (int j=0;j<4;j++){
        int m = mb + j;
        float val = acc[mi][ni][j] + bn;
        int bb = m >> 10, tp = m & 1023;
        if (cls == 2)
          vtb[(((size_t)(bb*16 + hh))*64 + hd)*1024 + tp] = f2bf(val);
        else {
          us* out = cls ? kbuf : qbuf;
          out[(((size_t)(bb*16 + hh))*1024 + tp)*64 + hd] = f2bf(val);
        }
      }
    }
  }
}

// ---------------- 3: O GEMM: 3 products, BM=128, BN=64, fp32 out ----------------
__global__ __launch_bounds__(256, 2) void k_gemmo(const us* __restrict__ A_hi, const us* __restrict__ A_lo,
                                                  const us* __restrict__ B_hi, const us* __restrict__ B_lo,
                                                  const float* __restrict__ bias,
                                                  float* __restrict__ out_f)
{
  __shared__ __align__(16) us a_lds[2][4096];
  __shared__ __align__(16) us b_lds[2][2048];
  int bid = blockIdx.x;
  int wg = (bid & 7) * 64 + (bid >> 3);        // 512 % 8 == 0
  int mt = wg >> 4, nt = wg & 15;
  int m0 = mt * 128, n0 = nt * 64;
  int t = threadIdx.x, w = t >> 6, lane = t & 63, lg = lane >> 4, li = lane & 15;
  int wm = w >> 1, wn = w & 1;
  f32x4 acc[4][2];
#pragma unroll
  for (int i=0;i<4;i++){ acc[i][0]=fzero(); acc[i][1]=fzero(); }

  auto stage = [&](int buf, int kt){
    int seg = kt >> 5, k0 = (kt & 31) * 32;
    const us* Ap = (seg == 2) ? A_lo : A_hi;
    const us* Bp = (seg == 1) ? B_lo : B_hi;
#pragma unroll
    for (int c = 0; c < 2; c++){
      int slot = c*256 + t;
      int g = slot ^ ((slot >> 3) & 7);
      int r = g >> 2, kc = g & 3;
      gload_lds16(Ap + (size_t)(m0 + r)*1024 + k0 + kc*8, (char*)&a_lds[buf][0] + slot*16);
    }
    {
      int slot = t;
      int g = slot ^ ((slot >> 3) & 7);
      int r = g >> 2, kc = g & 3;
      gload_lds16(Bp + (size_t)(n0 + r)*1024 + k0 + kc*8, (char*)&b_lds[buf][0] + slot*16);
    }
  };

  stage(0, 0);
  __syncthreads();
  int buf = 0;
  for (int kt = 0; kt < 96; kt++){
    if (kt + 1 < 96) stage(buf ^ 1, kt + 1);
    bf16x8 af[4], bfv[2];
#pragma unroll
    for (int mi=0;mi<4;mi++){
      int r = wm*64 + mi*16 + li;
      int s = (r*4 + lg); s ^= ((s >> 3) & 7);
      af[mi] = *(const bf16x8*)((char*)&a_lds[buf][0] + s*16);
    }
#pragma unroll
    for (int ni=0;ni<2;ni++){
      int r = wn*32 + ni*16 + li;
      int s = (r*4 + lg); s ^= ((s >> 3) & 7);
      bfv[ni] = *(const bf16x8*)((char*)&b_lds[buf][0] + s*16);
    }
#pragma unroll
    for (int mi=0;mi<4;mi++)
#pragma unroll
      for (int ni=0;ni<2;ni++)
        acc[mi][ni] = mfma16(af[mi], bfv[ni], acc[mi][ni]);
    __syncthreads();
    buf ^= 1;
  }

#pragma unroll
  for (int ni=0;ni<2;ni++){
    int n = n0 + wn*32 + ni*16 + li;
    float bn = bias[n];
#pragma unroll
    for (int mi=0;mi<4;mi++){
      int mb = m0 + wm*64 + mi*16 + lg*4;
#pragma unroll
      for (int j=0;j<4;j++)
        out_f[(size_t)(mb + j)*1024 + n] = acc[mi][ni][j] + bn;
    }
  }
}

// ---------------- 4: c2p/p2c (single product, pre-scaled by BS for exp2) ----------------
__global__ __launch_bounds__(256) void k_cp(const us* __restrict__ q_hi,
                                            const us* __restrict__ k_hi,
                                            const us* __restrict__ pk_hi,
                                            const us* __restrict__ pq_hi,
                                            us* __restrict__ c2p, us* __restrict__ p2c)
{
  int qt = blockIdx.x, bh = blockIdx.y, z = blockIdx.z;
  const us* X_hi = z ? k_hi : q_hi;
  const us* P_hi = z ? pq_hi : pk_hi;
  us* out = z ? p2c : c2p;
  int h = bh & 15;
  int t = threadIdx.x, w = t >> 6, lane = t & 63, lg = lane >> 4, li = lane & 15;
  f32x4 acc[4];
#pragma unroll
  for (int i=0;i<4;i++) acc[i] = fzero();
  size_t row = (size_t)bh*1024 + qt*64 + w*16 + li;
#pragma unroll
  for (int kk=0;kk<2;kk++){
    int k = kk*32 + lg*8;
    bf16x8 ah = *(const bf16x8*)(X_hi + row*64 + k);
#pragma unroll
    for (int nf=0;nf<4;nf++){
      int s = nf*16 + li;
      bf16x8 bh_ = *(const bf16x8*)(P_hi + (size_t)h*4096 + s*64 + k);
      acc[nf] = mfma16(ah, bh_, acc[nf]);
    }
  }
  size_t obase = ((size_t)bh*1024 + qt*64 + w*16 + lg*4) * 64;
#pragma unroll
  for (int nf=0;nf<4;nf++)
#pragma unroll
    for (int j=0;j<4;j++)
      out[obase + (size_t)j*64 + nf*16 + li] = f2bf(acc[nf][j] * BS);
}

// ---------------- 5: fused attention: 8 waves, QBLK=128, far fast path ----------------
__global__ __launch_bounds__(512) void k_attn(const us* __restrict__ qhi,
                                              const us* __restrict__ khi,
                                              const us* __restrict__ vhi,
                                              const us* __restrict__ c2p, const us* __restrict__ p2c,
                                              const signed char* __restrict__ idxt,
                                              const unsigned char* __restrict__ mask,
                                              us* __restrict__ ctx_hi, us* __restrict__ ctx_lo)
{
  __shared__ __align__(16) us khi_lds[4096], vhi_lds[4096];
  __shared__ __align__(16) us c2p_lds[128*72], p2c_lds[64*72];   // padded rows: 144B stride
  __shared__ __align__(16) us p_lds[8][1024];
  __shared__ signed char idx_lds[2048];

  const int qt = blockIdx.x, bh = blockIdx.y;   // qt: 0..7
  const int b = bh >> 4, h = bh & 15;
  const int t = threadIdx.x, w = t >> 6, lane = t & 63, lg = lane >> 4, li = lane & 15;
  const int q0 = qt * 128;

  for (int i = t; i < 2047; i += 512) idx_lds[i] = idxt[i];
  {
    const us* src = c2p + ((size_t)bh*1024 + q0) * 64;
#pragma unroll
    for (int c = 0; c < 2; c++){
      int f = c*512 + t, r = f >> 3, kc = f & 7;
      *(ushort8*)&c2p_lds[r*72 + kc*8] = *(const ushort8*)(src + r*64 + kc*8);
    }
  }
  bf16x8 qfh[2];
  {
    const us* qph = qhi + ((size_t)bh*1024 + q0 + w*16 + li)*64 + lg*8;
    qfh[0] = *(const bf16x8*)(qph); qfh[1] = *(const bf16x8*)(qph + 32);
  }
  __syncthreads();
  // far-path per-row bias (scaled) for idx=0 / idx=63
  float cq0[4], cq63[4];
#pragma unroll
  for (int j=0;j<4;j++){
    int qloc = w*16 + lg*4 + j;
    cq0[j]  = b2f(c2p_lds[qloc*72 + 0]);
    cq63[j] = b2f(c2p_lds[qloc*72 + 63]);
  }

  float lrow[4];
  f32x4 accO[4];
#pragma unroll
  for (int j=0;j<4;j++){ lrow[j] = 0.f; accO[j] = fzero(); }
  const unsigned char* mptr = mask + b*1024;

  for (int kt = 0; kt < 16; kt++){
    const int k0 = kt * 64;
    const bool far = (q0 - k0 >= 192) || (k0 - q0 >= 256);
    __syncthreads();
    {  // stage K,V: one 16B chunk each per thread
      int r = t >> 3, kc = t & 7;
      *(ushort8*)&khi_lds[r*64 + ((kc ^ (r & 7))*8)] =
          *(const ushort8*)(khi + ((size_t)bh*1024 + k0 + r)*64 + kc*8);
      *(ushort8*)&vhi_lds[r*64 + ((kc ^ (r & 7))*8)] =
          *(const ushort8*)(vhi + ((size_t)bh*64 + r)*1024 + k0 + kc*8);
      if (!far)
        *(ushort8*)&p2c_lds[r*72 + kc*8] =
            *(const ushort8*)(p2c + ((size_t)bh*1024 + k0 + r)*64 + kc*8);
    }
    __syncthreads();

    // QK^T single product
    f32x4 sfr[4];
#pragma unroll
    for (int nf=0;nf<4;nf++) sfr[nf] = fzero();
#pragma unroll
    for (int kk=0; kk<2; kk++){
      int kc = kk*4 + lg;
#pragma unroll
      for (int nf=0; nf<4; nf++){
        int r = nf*16 + li;
        bf16x8 bh_ = *(const bf16x8*)&khi_lds[r*64 + ((kc ^ (r & 7))*8)];
        sfr[nf] = mfma16(qfh[kk], bh_, sfr[nf]);
      }
    }
    us* pl = &p_lds[w][0];
    if (far){
      const int cidx = (q0 > k0) ? 63 : 0;
      float cq[4];
#pragma unroll
      for (int j=0;j<4;j++) cq[j] = (q0 > k0) ? cq63[j] : cq0[j];
#pragma unroll
      for (int nf=0; nf<4; nf++){
        int kloc = nf*16 + li;
        bool mk = mptr[k0 + kloc] != 0;
        float ck = b2f(p2c[((size_t)bh*1024 + k0 + kloc)*64 + cidx]);
        int col = kloc;
#pragma unroll
        for (int j=0;j<4;j++){
          float p = mk ? 0.f : exp2f(fmaf(sfr[nf][j], QS2, cq[j] + ck));
          lrow[j] += p;
          int row = lg*4 + j;
          pl[row*64 + ((col & 7) | ((((col >> 3) ^ (row & 7))) << 3))] = f2bf(p);
        }
      }
    } else {
#pragma unroll
      for (int nf=0; nf<4; nf++){
        int kloc = nf*16 + li;
        bool mk = mptr[k0 + kloc] != 0;
        int col = kloc;
#pragma unroll
        for (int j=0;j<4;j++){
          int qloc = w*16 + lg*4 + j;
          int d = (q0 + qloc) - (k0 + kloc);
          int idx = (int)idx_lds[d + 1023];
          float s2 = fmaf(sfr[nf][j], QS2,
                          b2f(c2p_lds[qloc*72 + idx]) + b2f(p2c_lds[kloc*72 + idx]));
          float p = mk ? 0.f : exp2f(s2);
          lrow[j] += p;
          int row = lg*4 + j;
          pl[row*64 + ((col & 7) | ((((col >> 3) ^ (row & 7))) << 3))] = f2bf(p);
        }
      }
    }
    // PV single product (p_lds wave-private; same-wave DS ordering)
#pragma unroll
    for (int kk=0;kk<2;kk++){
      int kc = kk*4 + lg;
      bf16x8 af = *(const bf16x8*)((char*)pl + li*128 + ((kc ^ (li & 7)) * 16));
#pragma unroll
      for (int nf=0;nf<4;nf++){
        int r = nf*16 + li;
        bf16x8 bh_ = *(const bf16x8*)&vhi_lds[r*64 + ((kc ^ (r & 7))*8)];
        accO[nf] = mfma16(af, bh_, accO[nf]);
      }
    }
  }

  for (int o=1;o<16;o<<=1)
#pragma unroll
    for (int j=0;j<4;j++)
      lrow[j] += __shfl_xor(lrow[j], o);
#pragma unroll
  for (int nf=0;nf<4;nf++)
#pragma unroll
    for (int j=0;j<4;j++){
      int qloc = w*16 + lg*4 + j;
      float o = accO[nf][j] / lrow[j];
      size_t idx = ((size_t)(b*1024 + q0 + qloc))*1024 + h*64 + nf*16 + li;
      us hh,ll; split2(o,hh,ll);
      ctx_hi[idx] = hh; ctx_lo[idx] = ll;
    }
}

// ---------------- launch ----------------
extern "C" void kernel_launch(void* const* d_in, const int* in_sizes, int n_in,
                              void* d_out, int out_size, void* d_ws, size_t ws_size,
                              hipStream_t stream)
{
  (void)in_sizes; (void)n_in; (void)out_size; (void)ws_size;
  const float* query = (const float*)d_in[0];
  const float* kvst  = (const float*)d_in[1];
  const unsigned char* mask = (const unsigned char*)d_in[2];
  const float* Wq = (const float*)d_in[3];  const float* bq = (const float*)d_in[4];
  const float* Wk = (const float*)d_in[5];  const float* bk = (const float*)d_in[6];
  const float* Wv = (const float*)d_in[7];  const float* bv = (const float*)d_in[8];
  const float* Wo = (const float*)d_in[9];  const float* bo = (const float*)d_in[10];
  const float* rel = (const float*)d_in[11];
  const float* lng = (const float*)d_in[12]; const float* lnb = (const float*)d_in[13];
  const float* Wpk = (const float*)d_in[14]; const float* bpk = (const float*)d_in[15];
  const float* Wpq = (const float*)d_in[16]; const float* bpq = (const float*)d_in[17];

  char* ws = (char*)d_ws;
  const size_t MB = 1024*1024;
  // layout (alias-safe by execution order):
  us* Xq_hi  = (us*)(ws + 0);        // dead after k_qkvp
  us* p2c    = (us*)(ws + 8*MB);     // written by k_cp (after k_qkvp)
  us* Xkv_hi = (us*)(ws + 16*MB);    // dead after k_qkvp
  us* c2p    = (us*)(ws + 16*MB);    // written by k_cp
  us* vtb_hi = (us*)(ws + 24*MB);    // written by k_qkvp (V class)
  us* Wt     = (us*)(ws + 32*MB);    // 6 slots x 4MB (hi 2MB + lo 2MB)
  us* ctx_hi = (us*)(ws + 32*MB);    // over Wq/Wk slots (dead after k_qkvp)
  us* ctx_lo = (us*)(ws + 40*MB);    // over Wv/Wpk slots (dead after k_qkvp)
  us* reln_hi = (us*)(ws + 56*MB);
  us* posk_hi = (us*)(ws + 56*MB + 256*1024);
  us* posq_hi = (us*)(ws + 56*MB + 512*1024);
  signed char* idxt = (signed char*)(ws + 56*MB + 768*1024);
  us* qbuf_hi = (us*)(ws + 57*MB);
  us* kbuf_hi = (us*)(ws + 65*MB);

  k_prep<<<14409, 256, 0, stream>>>(query, kvst, Wq, Wk, Wv, Wpk, Wpq, Wo,
                                    rel, lng, lnb,
                                    Xq_hi, Xkv_hi, Wt, reln_hi, idxt);

  k_qkvp<<<800, 256, 0, stream>>>(Xq_hi, Xkv_hi, Wt, bq, bk, bv,
                                  reln_hi, bpk, bpq,
                                  qbuf_hi, kbuf_hi, vtb_hi, posk_hi, posq_hi);

  k_cp<<<dim3(16,64,2), 256, 0, stream>>>(qbuf_hi, kbuf_hi, posk_hi, posq_hi, c2p, p2c);

  k_attn<<<dim3(8,64), 512, 0, stream>>>(qbuf_hi, kbuf_hi, vtb_hi,
                                         c2p, p2c, idxt, mask, ctx_hi, ctx_lo);

  k_gemmo<<<512, 256, 0, stream>>>(ctx_hi, ctx_lo, Wt + 5*2097152, Wt + 5*2097152 + 1048576, bo, (float*)d_out);
}

// Round 9
// 201.525 us; speedup vs baseline: 2.0025x; 1.1315x over previous
//
#include <hip/hip_runtime.h>
#include <cstdint>
#include <math.h>

typedef unsigned short us;
typedef __attribute__((ext_vector_type(8))) __bf16 bf16x8;
typedef __attribute__((ext_vector_type(8))) unsigned short ushort8;
typedef __attribute__((ext_vector_type(4))) float f32x4;

__device__ __forceinline__ us f2bf(float x){
  union { float f; unsigned int u; } v; v.f = x;
  unsigned int r = v.u + 0x7FFFu + ((v.u >> 16) & 1u);   // RNE
  return (us)(r >> 16);
}
__device__ __forceinline__ float b2f(us u){
  union { unsigned int u; float f; } v; v.u = ((unsigned int)u) << 16; return v.f;
}
__device__ __forceinline__ void split2(float x, us& hi, us& lo){
  hi = f2bf(x); lo = f2bf(x - b2f(hi));
}
__device__ __forceinline__ f32x4 fzero(){ f32x4 v; v.x=0.f; v.y=0.f; v.z=0.f; v.w=0.f; return v; }
__device__ __forceinline__ f32x4 mfma16(bf16x8 a, bf16x8 b, f32x4 c){
  return __builtin_amdgcn_mfma_f32_16x16x32_bf16(a, b, c, 0, 0, 0);
}
__device__ __forceinline__ void gload_lds16(const void* g, void* l){
  __builtin_amdgcn_global_load_lds(
      (const __attribute__((address_space(1))) unsigned int*)(uintptr_t)g,
      (__attribute__((address_space(3))) unsigned int*)(uintptr_t)l,
      16, 0, 0);
}

// exp2-folded scales
#define QS2 (0.07216878364870322f * 1.4426950408889634f)   // 1/sqrt(192) * log2(e)
#define BS  (0.08838834764831845f * 1.4426950408889634f)   // 1/sqrt(128) * log2(e)

// ---------------- 1: fused prep: convx | convw | lnrel | bucket ----------------
__global__ __launch_bounds__(256) void k_prep(const float* __restrict__ xq,
                                              const float* __restrict__ xkv,
                                              const float* __restrict__ w0, const float* __restrict__ w1,
                                              const float* __restrict__ w2, const float* __restrict__ w3,
                                              const float* __restrict__ w4, const float* __restrict__ w5,
                                              const float* __restrict__ rel,
                                              const float* __restrict__ g, const float* __restrict__ bLN,
                                              us* __restrict__ qhi, us* __restrict__ kvhi,
                                              us* __restrict__ wt, us* __restrict__ reln_hi,
                                              signed char* __restrict__ idxt)
{
  __shared__ float tile[32][33];
  __shared__ float sm[8];
  const int bid = blockIdx.x, t = threadIdx.x;

  if (bid < 8192){                      // ---- convx (hi only)
    int i = bid * 256 + t;
    const float* src; us* dh;
    if (i < 1048576){ src = xq  + (size_t)i*4;           dh = qhi  + (size_t)i*4; }
    else            { src = xkv + (size_t)(i-1048576)*4; dh = kvhi + (size_t)(i-1048576)*4; }
    f32x4 v = *(const f32x4*)src;
    dh[0]=f2bf(v.x); dh[1]=f2bf(v.y); dh[2]=f2bf(v.z); dh[3]=f2bf(v.w);
    return;
  }
  if (bid < 14336){                     // ---- convw: transpose + hi/lo split
    int rem = bid - 8192;
    int z = rem >> 10, r2 = rem & 1023;
    const float* W = (z==0)?w0:(z==1)?w1:(z==2)?w2:(z==3)?w3:(z==4)?w4:w5;
    us* dst_hi = wt + (size_t)z * 2097152;
    us* dst_lo = dst_hi + 1048576;
    bool wlo = (z == 2) || (z == 5);
    int n0 = (r2 & 31) * 32, k0 = (r2 >> 5) * 32;
    int c = t & 31, r = t >> 5;
#pragma unroll
    for (int i = 0; i < 4; i++)
      tile[r + i*8][c] = W[(size_t)(k0 + r + i*8)*1024 + n0 + c];
    __syncthreads();
#pragma unroll
    for (int i = 0; i < 4; i++){
      int nn = r + i*8;
      us h,l; split2(tile[c][nn], h, l);
      dst_hi[(size_t)(n0 + nn)*1024 + k0 + c] = h;
      if (wlo) dst_lo[(size_t)(n0 + nn)*1024 + k0 + c] = l;
    }
    return;
  }
  if (bid < 14400){                     // ---- lnrel
    int row = bid - 14336;
    const float* x = rel + (size_t)row * 1024;
    float v[4]; float s = 0.f, ss = 0.f;
#pragma unroll
    for (int i=0;i<4;i++){ v[i] = x[t + 256*i]; s += v[i]; ss += v[i]*v[i]; }
    for (int o=32;o;o>>=1){ s += __shfl_xor(s,o); ss += __shfl_xor(ss,o); }
    int w = t >> 6;
    if ((t & 63) == 0){ sm[w] = s; sm[4+w] = ss; }
    __syncthreads();
    s  = sm[0]+sm[1]+sm[2]+sm[3];
    ss = sm[4]+sm[5]+sm[6]+sm[7];
    float mu  = s  * (1.0f/1024.0f);
    float var = ss * (1.0f/1024.0f) - mu*mu;
    float rs  = rsqrtf(var + 1e-5f);
#pragma unroll
    for (int i=0;i<4;i++){
      int cc = t + 256*i;
      reln_hi[(size_t)row*1024 + cc] = f2bf((v[i]-mu)*rs*g[cc] + bLN[cc]);
    }
    return;
  }
  {                                     // ---- bucket table
    int i = (bid - 14400) * 256 + t;
    if (i >= 2052) return;
    int d = i - 1023;
    int ad = d < 0 ? -d : d;
    int abspos = (d < 16 && d > -16) ? 15 : ad;
    int bucket;
    if (abspos <= 16) bucket = d;
    else {
      float num = (float)log((double)abspos * 0.0625);
      float den = (float)log(7.9375);
      float lp = ceilf(num / den * 15.0f) + 16.0f;
      bucket = (int)lp * (d > 0 ? 1 : -1);
    }
    int s = bucket + 32;
    s = s < 0 ? 0 : (s > 63 ? 63 : s);
    idxt[i] = (signed char)s;
  }
}

// ---------------- 2: merged QKV GEMM (BM=128, BN=128) + pos projections ----------------
// cls = bid>>8: classes contiguous in bid -> round-robin XCD spreads each class over all 8 XCDs.
// Within class: XCD gets contiguous 32-tile chunk (4 A-panel rows) for L2 locality.
__global__ __launch_bounds__(256) void k_qkvp(const us* __restrict__ Xq, const us* __restrict__ Xkv,
                                              const us* __restrict__ wt,
                                              const float* __restrict__ bq, const float* __restrict__ bk,
                                              const float* __restrict__ bv,
                                              const us* __restrict__ reln_hi,
                                              const float* __restrict__ bpk, const float* __restrict__ bpq,
                                              us* __restrict__ qbuf, us* __restrict__ kbuf,
                                              us* __restrict__ vtb,
                                              us* __restrict__ posk_hi, us* __restrict__ posq_hi)
{
  __shared__ __align__(16) us a_lds[2][4096];   // 128 x 32
  __shared__ __align__(16) us b_lds[2][4096];   // 128 x 32
  const int bid = blockIdx.x;
  const int t = threadIdx.x, w = t >> 6, lane = t & 63, lg = lane >> 4, li = lane & 15;

  if (bid >= 768){                      // ---- pos projections (32 blocks)
    int wg2 = bid - 768;
    int ntile = wg2 & 15, z = wg2 >> 4;
    const us* W_hi = wt + (size_t)(3 + z) * 2097152;
    const float* bias = z ? bpq : bpk;
    us* out_hi = z ? posq_hi : posk_hi;
    f32x4 acc[4];
#pragma unroll
    for (int i=0;i<4;i++) acc[i] = fzero();
    int srow = w*16 + li;
    for (int kt = 0; kt < 32; kt++){
      int k0 = kt*32 + lg*8;
      bf16x8 a = *(const bf16x8*)(reln_hi + (size_t)srow*1024 + k0);
#pragma unroll
      for (int nf=0; nf<4; nf++){
        int n = ntile*64 + nf*16 + li;
        bf16x8 b = *(const bf16x8*)(W_hi + (size_t)n*1024 + k0);
        acc[nf] = mfma16(a, b, acc[nf]);
      }
    }
#pragma unroll
    for (int nf=0;nf<4;nf++){
      int n = ntile*64 + nf*16 + li;
      float bn = bias[n];
      int h = n >> 6, hd = n & 63;
#pragma unroll
      for (int j=0;j<4;j++){
        int s = w*16 + lg*4 + j;
        out_hi[(size_t)h*4096 + s*64 + hd] = f2bf(acc[nf][j] + bn);
      }
    }
    return;
  }

  // ---- QKV classes: balanced across XCDs
  int cls = bid >> 8;                          // 0:Q 1:K 2:V — each spans all XCDs
  int u = bid & 255;
  int tile = (u & 7) * 32 + (u >> 3);          // XCD-contiguous tile chunk
  int mt = tile >> 3, nt = tile & 7;
  int m0 = mt * 128, n0 = nt * 128;
  const us* A  = (cls == 0) ? Xq : Xkv;
  const us* Bh = wt + (size_t)cls * 2097152;
  const us* Bl = Bh + 1048576;
  const float* bias = (cls==0) ? bq : (cls==1) ? bk : bv;
  const int NKT = (cls == 2) ? 64 : 32;
  int wm = w >> 1, wn = w & 1;
  f32x4 acc[4][4];
#pragma unroll
  for (int i=0;i<4;i++)
#pragma unroll
    for (int j=0;j<4;j++) acc[i][j] = fzero();

  auto stage = [&](int buf, int kt){
    int seg = kt >> 5, k0 = (kt & 31) * 32;
    const us* Bp = seg ? Bl : Bh;
#pragma unroll
    for (int c = 0; c < 2; c++){
      int slot = c*256 + t;
      int g = slot ^ ((slot >> 3) & 7);
      int r = g >> 2, kc = g & 3;
      gload_lds16(A  + (size_t)(m0 + r)*1024 + k0 + kc*8, (char*)&a_lds[buf][0] + slot*16);
      gload_lds16(Bp + (size_t)(n0 + r)*1024 + k0 + kc*8, (char*)&b_lds[buf][0] + slot*16);
    }
  };

  stage(0, 0);
  __syncthreads();
  int buf = 0;
  for (int kt = 0; kt < NKT; kt++){
    if (kt + 1 < NKT) stage(buf ^ 1, kt + 1);
    bf16x8 af[4], bfv[4];
#pragma unroll
    for (int mi=0;mi<4;mi++){
      int r = wm*64 + mi*16 + li;
      int s = (r*4 + lg); s ^= ((s >> 3) & 7);
      af[mi] = *(const bf16x8*)((char*)&a_lds[buf][0] + s*16);
    }
#pragma unroll
    for (int ni=0;ni<4;ni++){
      int r = wn*64 + ni*16 + li;
      int s = (r*4 + lg); s ^= ((s >> 3) & 7);
      bfv[ni] = *(const bf16x8*)((char*)&b_lds[buf][0] + s*16);
    }
#pragma unroll
    for (int mi=0;mi<4;mi++)
#pragma unroll
      for (int ni=0;ni<4;ni++)
        acc[mi][ni] = mfma16(af[mi], bfv[ni], acc[mi][ni]);
    __syncthreads();
    buf ^= 1;
  }

#pragma unroll
  for (int ni=0;ni<4;ni++){
    int n = n0 + wn*64 + ni*16 + li;
    float bn = bias[n];
    int hh = n >> 6, hd = n & 63;
#pragma unroll
    for (int mi=0;mi<4;mi++){
      int mb = m0 + wm*64 + mi*16 + lg*4;
#pragma unroll
      for (int j=0;j<4;j++){
        int m = mb + j;
        float val = acc[mi][ni][j] + bn;
        int bb = m >> 10, tp = m & 1023;
        if (cls == 2)
          vtb[(((size_t)(bb*16 + hh))*64 + hd)*1024 + tp] = f2bf(val);
        else {
          us* out = cls ? kbuf : qbuf;
          out[(((size_t)(bb*16 + hh))*1024 + tp)*64 + hd] = f2bf(val);
        }
      }
    }
  }
}

// ---------------- 3: O GEMM: 3 products, BM=128, BN=64, fp32 out ----------------
__global__ __launch_bounds__(256, 2) void k_gemmo(const us* __restrict__ A_hi, const us* __restrict__ A_lo,
                                                  const us* __restrict__ B_hi, const us* __restrict__ B_lo,
                                                  const float* __restrict__ bias,
                                                  float* __restrict__ out_f)
{
  __shared__ __align__(16) us a_lds[2][4096];
  __shared__ __align__(16) us b_lds[2][2048];
  int bid = blockIdx.x;
  int wg = (bid & 7) * 64 + (bid >> 3);        // 512 % 8 == 0
  int mt = wg >> 4, nt = wg & 15;
  int m0 = mt * 128, n0 = nt * 64;
  int t = threadIdx.x, w = t >> 6, lane = t & 63, lg = lane >> 4, li = lane & 15;
  int wm = w >> 1, wn = w & 1;
  f32x4 acc[4][2];
#pragma unroll
  for (int i=0;i<4;i++){ acc[i][0]=fzero(); acc[i][1]=fzero(); }

  auto stage = [&](int buf, int kt){
    int seg = kt >> 5, k0 = (kt & 31) * 32;
    const us* Ap = (seg == 2) ? A_lo : A_hi;
    const us* Bp = (seg == 1) ? B_lo : B_hi;
#pragma unroll
    for (int c = 0; c < 2; c++){
      int slot = c*256 + t;
      int g = slot ^ ((slot >> 3) & 7);
      int r = g >> 2, kc = g & 3;
      gload_lds16(Ap + (size_t)(m0 + r)*1024 + k0 + kc*8, (char*)&a_lds[buf][0] + slot*16);
    }
    {
      int slot = t;
      int g = slot ^ ((slot >> 3) & 7);
      int r = g >> 2, kc = g & 3;
      gload_lds16(Bp + (size_t)(n0 + r)*1024 + k0 + kc*8, (char*)&b_lds[buf][0] + slot*16);
    }
  };

  stage(0, 0);
  __syncthreads();
  int buf = 0;
  for (int kt = 0; kt < 96; kt++){
    if (kt + 1 < 96) stage(buf ^ 1, kt + 1);
    bf16x8 af[4], bfv[2];
#pragma unroll
    for (int mi=0;mi<4;mi++){
      int r = wm*64 + mi*16 + li;
      int s = (r*4 + lg); s ^= ((s >> 3) & 7);
      af[mi] = *(const bf16x8*)((char*)&a_lds[buf][0] + s*16);
    }
#pragma unroll
    for (int ni=0;ni<2;ni++){
      int r = wn*32 + ni*16 + li;
      int s = (r*4 + lg); s ^= ((s >> 3) & 7);
      bfv[ni] = *(const bf16x8*)((char*)&b_lds[buf][0] + s*16);
    }
#pragma unroll
    for (int mi=0;mi<4;mi++)
#pragma unroll
      for (int ni=0;ni<2;ni++)
        acc[mi][ni] = mfma16(af[mi], bfv[ni], acc[mi][ni]);
    __syncthreads();
    buf ^= 1;
  }

#pragma unroll
  for (int ni=0;ni<2;ni++){
    int n = n0 + wn*32 + ni*16 + li;
    float bn = bias[n];
#pragma unroll
    for (int mi=0;mi<4;mi++){
      int mb = m0 + wm*64 + mi*16 + lg*4;
#pragma unroll
      for (int j=0;j<4;j++)
        out_f[(size_t)(mb + j)*1024 + n] = acc[mi][ni][j] + bn;
    }
  }
}

// ---------------- 4: c2p/p2c (single product, pre-scaled by BS for exp2) ----------------
__global__ __launch_bounds__(256) void k_cp(const us* __restrict__ q_hi,
                                            const us* __restrict__ k_hi,
                                            const us* __restrict__ pk_hi,
                                            const us* __restrict__ pq_hi,
                                            us* __restrict__ c2p, us* __restrict__ p2c)
{
  int qt = blockIdx.x, bh = blockIdx.y, z = blockIdx.z;
  const us* X_hi = z ? k_hi : q_hi;
  const us* P_hi = z ? pq_hi : pk_hi;
  us* out = z ? p2c : c2p;
  int h = bh & 15;
  int t = threadIdx.x, w = t >> 6, lane = t & 63, lg = lane >> 4, li = lane & 15;
  f32x4 acc[4];
#pragma unroll
  for (int i=0;i<4;i++) acc[i] = fzero();
  size_t row = (size_t)bh*1024 + qt*64 + w*16 + li;
#pragma unroll
  for (int kk=0;kk<2;kk++){
    int k = kk*32 + lg*8;
    bf16x8 ah = *(const bf16x8*)(X_hi + row*64 + k);
#pragma unroll
    for (int nf=0;nf<4;nf++){
      int s = nf*16 + li;
      bf16x8 bh_ = *(const bf16x8*)(P_hi + (size_t)h*4096 + s*64 + k);
      acc[nf] = mfma16(ah, bh_, acc[nf]);
    }
  }
  size_t obase = ((size_t)bh*1024 + qt*64 + w*16 + lg*4) * 64;
#pragma unroll
  for (int nf=0;nf<4;nf++)
#pragma unroll
    for (int j=0;j<4;j++)
      out[obase + (size_t)j*64 + nf*16 + li] = f2bf(acc[nf][j] * BS);
}

// ---------------- 5: fused attention: 8 waves, QBLK=128, far fast path ----------------
__global__ __launch_bounds__(512) void k_attn(const us* __restrict__ qhi,
                                              const us* __restrict__ khi,
                                              const us* __restrict__ vhi,
                                              const us* __restrict__ c2p, const us* __restrict__ p2c,
                                              const signed char* __restrict__ idxt,
                                              const unsigned char* __restrict__ mask,
                                              us* __restrict__ ctx_hi, us* __restrict__ ctx_lo)
{
  __shared__ __align__(16) us khi_lds[4096], vhi_lds[4096];
  __shared__ __align__(16) us c2p_lds[128*72], p2c_lds[64*72];   // padded rows: 144B stride
  __shared__ __align__(16) us p_lds[8][1024];
  __shared__ signed char idx_lds[2048];

  const int qt = blockIdx.x, bh = blockIdx.y;   // qt: 0..7
  const int b = bh >> 4, h = bh & 15;
  const int t = threadIdx.x, w = t >> 6, lane = t & 63, lg = lane >> 4, li = lane & 15;
  const int q0 = qt * 128;

  for (int i = t; i < 2047; i += 512) idx_lds[i] = idxt[i];
  {
    const us* src = c2p + ((size_t)bh*1024 + q0) * 64;
#pragma unroll
    for (int c = 0; c < 2; c++){
      int f = c*512 + t, r = f >> 3, kc = f & 7;
      *(ushort8*)&c2p_lds[r*72 + kc*8] = *(const ushort8*)(src + r*64 + kc*8);
    }
  }
  bf16x8 qfh[2];
  {
    const us* qph = qhi + ((size_t)bh*1024 + q0 + w*16 + li)*64 + lg*8;
    qfh[0] = *(const bf16x8*)(qph); qfh[1] = *(const bf16x8*)(qph + 32);
  }
  __syncthreads();
  // far-path per-row bias (scaled) for idx=0 / idx=63
  float cq0[4], cq63[4];
#pragma unroll
  for (int j=0;j<4;j++){
    int qloc = w*16 + lg*4 + j;
    cq0[j]  = b2f(c2p_lds[qloc*72 + 0]);
    cq63[j] = b2f(c2p_lds[qloc*72 + 63]);
  }

  float lrow[4];
  f32x4 accO[4];
#pragma unroll
  for (int j=0;j<4;j++){ lrow[j] = 0.f; accO[j] = fzero(); }
  const unsigned char* mptr = mask + b*1024;

  for (int kt = 0; kt < 16; kt++){
    const int k0 = kt * 64;
    const bool far = (q0 - k0 >= 192) || (k0 - q0 >= 256);
    __syncthreads();
    {  // stage K,V: one 16B chunk each per thread
      int r = t >> 3, kc = t & 7;
      *(ushort8*)&khi_lds[r*64 + ((kc ^ (r & 7))*8)] =
          *(const ushort8*)(khi + ((size_t)bh*1024 + k0 + r)*64 + kc*8);
      *(ushort8*)&vhi_lds[r*64 + ((kc ^ (r & 7))*8)] =
          *(const ushort8*)(vhi + ((size_t)bh*64 + r)*1024 + k0 + kc*8);
      if (!far)
        *(ushort8*)&p2c_lds[r*72 + kc*8] =
            *(const ushort8*)(p2c + ((size_t)bh*1024 + k0 + r)*64 + kc*8);
    }
    __syncthreads();

    // QK^T single product
    f32x4 sfr[4];
#pragma unroll
    for (int nf=0;nf<4;nf++) sfr[nf] = fzero();
#pragma unroll
    for (int kk=0; kk<2; kk++){
      int kc = kk*4 + lg;
#pragma unroll
      for (int nf=0; nf<4; nf++){
        int r = nf*16 + li;
        bf16x8 bh_ = *(const bf16x8*)&khi_lds[r*64 + ((kc ^ (r & 7))*8)];
        sfr[nf] = mfma16(qfh[kk], bh_, sfr[nf]);
      }
    }
    us* pl = &p_lds[w][0];
    if (far){
      const int cidx = (q0 > k0) ? 63 : 0;
      float cq[4];
#pragma unroll
      for (int j=0;j<4;j++) cq[j] = (q0 > k0) ? cq63[j] : cq0[j];
#pragma unroll
      for (int nf=0; nf<4; nf++){
        int kloc = nf*16 + li;
        bool mk = mptr[k0 + kloc] != 0;
        float ck = b2f(p2c[((size_t)bh*1024 + k0 + kloc)*64 + cidx]);
        int col = kloc;
#pragma unroll
        for (int j=0;j<4;j++){
          float p = mk ? 0.f : exp2f(fmaf(sfr[nf][j], QS2, cq[j] + ck));
          lrow[j] += p;
          int row = lg*4 + j;
          pl[row*64 + ((col & 7) | ((((col >> 3) ^ (row & 7))) << 3))] = f2bf(p);
        }
      }
    } else {
#pragma unroll
      for (int nf=0; nf<4; nf++){
        int kloc = nf*16 + li;
        bool mk = mptr[k0 + kloc] != 0;
        int col = kloc;
#pragma unroll
        for (int j=0;j<4;j++){
          int qloc = w*16 + lg*4 + j;
          int d = (q0 + qloc) - (k0 + kloc);
          int idx = (int)idx_lds[d + 1023];
          float s2 = fmaf(sfr[nf][j], QS2,
                          b2f(c2p_lds[qloc*72 + idx]) + b2f(p2c_lds[kloc*72 + idx]));
          float p = mk ? 0.f : exp2f(s2);
          lrow[j] += p;
          int row = lg*4 + j;
          pl[row*64 + ((col & 7) | ((((col >> 3) ^ (row & 7))) << 3))] = f2bf(p);
        }
      }
    }
    // PV single product (p_lds wave-private; same-wave DS ordering)
#pragma unroll
    for (int kk=0;kk<2;kk++){
      int kc = kk*4 + lg;
      bf16x8 af = *(const bf16x8*)((char*)pl + li*128 + ((kc ^ (li & 7)) * 16));
#pragma unroll
      for (int nf=0;nf<4;nf++){
        int r = nf*16 + li;
        bf16x8 bh_ = *(const bf16x8*)&vhi_lds[r*64 + ((kc ^ (r & 7))*8)];
        accO[nf] = mfma16(af, bh_, accO[nf]);
      }
    }
  }

  for (int o=1;o<16;o<<=1)
#pragma unroll
    for (int j=0;j<4;j++)
      lrow[j] += __shfl_xor(lrow[j], o);
#pragma unroll
  for (int nf=0;nf<4;nf++)
#pragma unroll
    for (int j=0;j<4;j++){
      int qloc = w*16 + lg*4 + j;
      float o = accO[nf][j] / lrow[j];
      size_t idx = ((size_t)(b*1024 + q0 + qloc))*1024 + h*64 + nf*16 + li;
      us hh,ll; split2(o,hh,ll);
      ctx_hi[idx] = hh; ctx_lo[idx] = ll;
    }
}

// ---------------- launch ----------------
extern "C" void kernel_launch(void* const* d_in, const int* in_sizes, int n_in,
                              void* d_out, int out_size, void* d_ws, size_t ws_size,
                              hipStream_t stream)
{
  (void)in_sizes; (void)n_in; (void)out_size; (void)ws_size;
  const float* query = (const float*)d_in[0];
  const float* kvst  = (const float*)d_in[1];
  const unsigned char* mask = (const unsigned char*)d_in[2];
  const float* Wq = (const float*)d_in[3];  const float* bq = (const float*)d_in[4];
  const float* Wk = (const float*)d_in[5];  const float* bk = (const float*)d_in[6];
  const float* Wv = (const float*)d_in[7];  const float* bv = (const float*)d_in[8];
  const float* Wo = (const float*)d_in[9];  const float* bo = (const float*)d_in[10];
  const float* rel = (const float*)d_in[11];
  const float* lng = (const float*)d_in[12]; const float* lnb = (const float*)d_in[13];
  const float* Wpk = (const float*)d_in[14]; const float* bpk = (const float*)d_in[15];
  const float* Wpq = (const float*)d_in[16]; const float* bpq = (const float*)d_in[17];

  char* ws = (char*)d_ws;
  const size_t MB = 1024*1024;
  // layout (alias-safe by execution order):
  us* Xq_hi  = (us*)(ws + 0);        // dead after k_qkvp
  us* p2c    = (us*)(ws + 8*MB);     // written by k_cp (after k_qkvp)
  us* Xkv_hi = (us*)(ws + 16*MB);    // dead after k_qkvp
  us* c2p    = (us*)(ws + 16*MB);    // written by k_cp
  us* vtb_hi = (us*)(ws + 24*MB);    // written by k_qkvp (V class)
  us* Wt     = (us*)(ws + 32*MB);    // 6 slots x 4MB (hi 2MB + lo 2MB)
  us* ctx_hi = (us*)(ws + 32*MB);    // over Wq/Wk slots (dead after k_qkvp)
  us* ctx_lo = (us*)(ws + 40*MB);    // over Wv/Wpk slots (dead after k_qkvp)
  us* reln_hi = (us*)(ws + 56*MB);
  us* posk_hi = (us*)(ws + 56*MB + 256*1024);
  us* posq_hi = (us*)(ws + 56*MB + 512*1024);
  signed char* idxt = (signed char*)(ws + 56*MB + 768*1024);
  us* qbuf_hi = (us*)(ws + 57*MB);
  us* kbuf_hi = (us*)(ws + 65*MB);

  k_prep<<<14409, 256, 0, stream>>>(query, kvst, Wq, Wk, Wv, Wpk, Wpq, Wo,
                                    rel, lng, lnb,
                                    Xq_hi, Xkv_hi, Wt, reln_hi, idxt);

  k_qkvp<<<800, 256, 0, stream>>>(Xq_hi, Xkv_hi, Wt, bq, bk, bv,
                                  reln_hi, bpk, bpq,
                                  qbuf_hi, kbuf_hi, vtb_hi, posk_hi, posq_hi);

  k_cp<<<dim3(16,64,2), 256, 0, stream>>>(qbuf_hi, kbuf_hi, posk_hi, posq_hi, c2p, p2c);

  k_attn<<<dim3(8,64), 512, 0, stream>>>(qbuf_hi, kbuf_hi, vtb_hi,
                                         c2p, p2c, idxt, mask, ctx_hi, ctx_lo);

  k_gemmo<<<512, 256, 0, stream>>>(ctx_hi, ctx_lo, Wt + 5*2097152, Wt + 5*2097152 + 1048576, bo, (float*)d_out);
}